// Round 13
// baseline (213.075 us; speedup 1.0000x reference)
//
#include <hip/hip_runtime.h>

#define N 343        // 7*7*7 tokens per window
#define NP 352       // padded to 11 tiles of 32
#define DIM 128
#define HEADS 4
#define DH 32

typedef float  f32x16 __attribute__((ext_vector_type(16)));
typedef float  float4v __attribute__((ext_vector_type(4)));
typedef short  short8 __attribute__((ext_vector_type(8)));
typedef unsigned uint4v __attribute__((ext_vector_type(4)));
typedef unsigned uint2v __attribute__((ext_vector_type(2)));

#define MFMA __builtin_amdgcn_mfma_f32_32x32x16_bf16

// ---- gfx950 packed bf16 convert (RNE) and cross-half swap -----------------
static __device__ __forceinline__ unsigned cvtpk_bf16(float lo, float hi) {
  unsigned r;
  asm("v_cvt_pk_bf16_f32 %0, %1, %2" : "=v"(r) : "v"(lo), "v"(hi));
  return r;
}
static __device__ __forceinline__ void swap32(unsigned &a, unsigned &b) {
  asm("v_permlane32_swap_b32 %0, %1" : "+v"(a), "+v"(b));
}
// native base-2 exponential (v_exp_f32 IS exp2 on CDNA)
static __device__ __forceinline__ float exp2v(float x) {
  float r;
  asm("v_exp_f32 %0, %1" : "=v"(r) : "v"(x));
  return r;
}
static __device__ __forceinline__ unsigned short bf16u(float a) {
  unsigned u = __builtin_bit_cast(unsigned, a);
  unsigned r = u + 0x7fffu + ((u >> 16) & 1u);
  return (unsigned short)(r >> 16);
}
static __device__ __forceinline__ void split2pk(float a, float b,
                                                unsigned &hi, unsigned &lo) {
  hi = cvtpk_bf16(a, b);
  float ra = a - __builtin_bit_cast(float, hi << 16);
  float rb = b - __builtin_bit_cast(float, hi & 0xffff0000u);
  lo = cvtpk_bf16(ra, rb);
}

// ---------------------------------------------------------------------------
// Kernel 1: bias gather pre-permuted into the 32x32 MFMA C-fragment order.
// ---------------------------------------------------------------------------
__global__ __launch_bounds__(256) void bias_kernel(
    const float* __restrict__ table, const int* __restrict__ rel,
    float* __restrict__ prep) {
  int row = blockIdx.x * 256 + threadIdx.x;
  if (row >= HEADS * 11 * 2 * NP) return;
  int i = row % NP;
  int t = row / NP;
  int half = t & 1;
  int tj = t >> 1;
  int jt = tj % 11;
  int h = tj / 11;
  float* dst = prep + (size_t)row * 16;
#pragma unroll
  for (int r = 0; r < 16; ++r) {
    int j = jt * 32 + (r & 3) + ((r >> 2) << 3) + (half << 2);
    float v;
    if (j >= N) v = -1.44e30f;
    else if (i >= N) v = 0.f;
    else v = table[rel[i * N + j] * HEADS + h] * 1.4426950408889634f;
    dst[r] = v;
  }
}

// ---------------------------------------------------------------------------
// Phase-2 flash loop, one 32-row M-tile, Q in registers. EXACT R11 semantics
// (measured 205 us total, absmax 7.8e-3). Max-tracking is REQUIRED: the
// no-max variant failed correctness twice as an isolated change (R9, R12) —
// do not remove it again.
// Kb: [352][40] col-swizzled by (row&24). Vt: [32][352] token-swizzled (d&24)
// — stride 352 measured better than 360 (1.45e7 vs 1.85e7 conflict cycles).
// ---------------------------------------------------------------------------
static __device__ __forceinline__ void attend(
    int i0, uint4v qAu, uint4v qBu,
    const unsigned short* __restrict__ Kb, const unsigned short* __restrict__ Vt,
    const float* __restrict__ bp, float* __restrict__ outw,
    int l31, int half, int swz) {
  short8 q0 = __builtin_bit_cast(short8, qAu);
  short8 q1 = __builtin_bit_cast(short8, qBu);
  const float* bpi = bp + (size_t)(i0 + l31) * 16;

  f32x16 O;
#pragma unroll
  for (int r = 0; r < 16; ++r) O[r] = 0.f;
  float m_run = -3.0e38f, l_run = 0.f;

  f32x16 Tn = *(const f32x16*)(bpi);      // prefetch bias tile 0
  for (int jt = 0; jt < 11; ++jt) {
    f32x16 T = Tn;                        // bias IS the MFMA C-input
    if (jt < 10) Tn = *(const f32x16*)(bpi + (size_t)(jt + 1) * 11264);

    const int krow = (jt * 32 + l31) * 40;
    short8 ka0 = *(const short8*)&Kb[krow + ((half * 8) ^ swz)];
    short8 ka1 = *(const short8*)&Kb[krow + ((half * 8 + 16) ^ swz)];
    T = MFMA(ka0, q0, T, 0, 0, 0);
    T = MFMA(ka1, q1, T, 0, 0, 0);

    float m0 = fmaxf(T[0], T[1]),   m1 = fmaxf(T[2], T[3]);
    float m2 = fmaxf(T[4], T[5]),   m3 = fmaxf(T[6], T[7]);
    float m4 = fmaxf(T[8], T[9]),   m5 = fmaxf(T[10], T[11]);
    float m6 = fmaxf(T[12], T[13]), m7 = fmaxf(T[14], T[15]);
    m0 = fmaxf(m0, m1); m2 = fmaxf(m2, m3);
    m4 = fmaxf(m4, m5); m6 = fmaxf(m6, m7);
    m0 = fmaxf(m0, m2); m4 = fmaxf(m4, m6);
    float pm = fmaxf(m0, m4);
    pm = fmaxf(pm, __shfl_xor(pm, 32, 64));

    if (__any(pm > m_run + 11.5f)) {      // deferred-max rescale (rare)
      float nm = fmaxf(m_run, pm);
      float f = exp2v(m_run - nm);
      l_run *= f;
      m_run = nm;
#pragma unroll
      for (int r = 0; r < 16; ++r) {
        int iD = (r & 3) + ((r >> 2) << 3) + (half << 2);
        O[r] *= __shfl(f, iD, 64);
      }
    }

    float p[16];
#pragma unroll
    for (int r = 0; r < 16; ++r) p[r] = exp2v(T[r] - m_run);
    float s0 = (p[0] + p[1]) + (p[2] + p[3]);
    float s1 = (p[4] + p[5]) + (p[6] + p[7]);
    float s2 = (p[8] + p[9]) + (p[10] + p[11]);
    float s3 = (p[12] + p[13]) + (p[14] + p[15]);
    float ps = (s0 + s1) + (s2 + s3);
    l_run += ps + __shfl_xor(ps, 32, 64);

    unsigned k0 = cvtpk_bf16(p[0], p[1]),   k1 = cvtpk_bf16(p[2], p[3]);
    unsigned k2 = cvtpk_bf16(p[4], p[5]),   k3 = cvtpk_bf16(p[6], p[7]);
    unsigned k4 = cvtpk_bf16(p[8], p[9]),   k5 = cvtpk_bf16(p[10], p[11]);
    unsigned k6 = cvtpk_bf16(p[12], p[13]), k7 = cvtpk_bf16(p[14], p[15]);
    swap32(k0, k2); swap32(k1, k3); swap32(k4, k6); swap32(k5, k7);
    uint4v u1 = {k0, k1, k2, k3};
    uint4v u2 = {k4, k5, k6, k7};
    short8 pa1 = __builtin_bit_cast(short8, u1);
    short8 pa2 = __builtin_bit_cast(short8, u2);

    const int vrow = l31 * 352 + jt * 32;
    short8 vb1 = *(const short8*)&Vt[vrow + ((half * 8) ^ swz)];
    short8 vb2 = *(const short8*)&Vt[vrow + ((half * 8 + 16) ^ swz)];
    O = MFMA(pa1, vb1, O, 0, 0, 0);
    O = MFMA(pa2, vb2, O, 0, 0, 0);
  }

  float inv = 1.0f / l_run;
#pragma unroll
  for (int r = 0; r < 16; ++r) {
    int iD = (r & 3) + ((r >> 2) << 3) + (half << 2);
    float invr = __shfl(inv, iD, 64);
    int i = i0 + iD;
    if (i < N) outw[(size_t)i * DIM + l31] = O[r] * invr;
  }
}

// ---------------------------------------------------------------------------
// Kernel 2: fused QKV projection + attention. One block per (window, head),
// 768 threads = 12 waves, one M-tile per wave (wave 11 = staging helper).
// Phase-1: T14 async-STAGE split + NEW double-buffered X/W staging -> ONE
// barrier per k-chunk (was 2). Write of chunk kc targets buf[kc&1]; barrier
// at iter kc-1 guarantees all reads of buf[kc&1] (iter kc-2) completed.
// LDS 86016 B (phase-1 2x21504 u16; phase-2 K/V aliased) -> still 1 block/CU.
// ---------------------------------------------------------------------------
__global__ __launch_bounds__(768, 3) void attn_kernel(
    const float* __restrict__ x, const float* __restrict__ wqkv,
    const float* __restrict__ prep, float* __restrict__ out) {
  const int b = blockIdx.x;
  const int sw = (b & 7) * ((int)gridDim.x >> 3) + (b >> 3);  // XCD swizzle
  const int h = sw & 3;
  const int w = sw >> 2;
  const int tid = threadIdx.x;
  const int lane = tid & 63;
  const int wv = tid >> 6;        // 0..11
  const int l31 = lane & 31;
  const int half = lane >> 5;

  __shared__ __align__(16) unsigned short lds[43008];   // 86016 B
  // phase-1 double buffers (21504 u16 each)
  unsigned short* Xh0 = lds;              // [352][24]
  unsigned short* Xl0 = lds + 8448;       // [352][24]
  unsigned short* Wh0 = lds + 16896;      // [96][24]
  unsigned short* Wl0 = lds + 19200;      // [96][24]
  unsigned short* Xh1 = lds + 21504;
  unsigned short* Xl1 = lds + 29952;
  unsigned short* Wh1 = lds + 38400;
  unsigned short* Wl1 = lds + 40704;
  // phase-2 (aliased over the arena)
  unsigned short* Kb = lds;               // [352][40]
  unsigned short* Vt = lds + 14080;       // [32][352]

  const float* xw = x + (size_t)w * (N * DIM);
  const int xsw = ((l31 >> 3) & 1) << 3;   // 1-bit swizzle for X/W frag reads
  const bool act = (wv < 11);

  // ---- staging geometry (fixed per thread) ----
  const int xrow0 = tid >> 2,  xg0 = (tid & 3) << 2;           // job 0 (all)
  const int idx1  = tid + 768;
  const int xrow1 = idx1 >> 2, xg1 = (idx1 & 3) << 2;          // job 1
  const bool hasx1 = (idx1 < 1408);
  const bool hasw  = (tid < 384);
  const int wc = tid % 96, wkg = (tid / 96) << 2;
  const int wcol = ((wc >> 5) << 7) + h * DH + (wc & 31);
  const int xgs0 = xg0 ^ (((xrow0 >> 3) & 1) << 3);
  const int xgs1 = xg1 ^ (((xrow1 >> 3) & 1) << 3);
  const int wkgs = wkg ^ (((wc >> 3) & 1) << 3);

  float4v xr0v = {0.f, 0.f, 0.f, 0.f}, xr1v = {0.f, 0.f, 0.f, 0.f};
  float wr0 = 0.f, wr1 = 0.f, wr2 = 0.f, wr3 = 0.f;

#define LOAD_STAGE(kc_)                                                     \
  {                                                                         \
    xr0v = *(const float4v*)(xw + xrow0 * DIM + (kc_) * 16 + xg0);          \
    xr1v[0] = 0.f; xr1v[1] = 0.f; xr1v[2] = 0.f; xr1v[3] = 0.f;             \
    if (hasx1 && xrow1 < N)                                                 \
      xr1v = *(const float4v*)(xw + xrow1 * DIM + (kc_) * 16 + xg1);        \
    if (hasw) {                                                             \
      const float* wp_ = wqkv + (size_t)((kc_) * 16 + wkg) * 384 + wcol;    \
      wr0 = wp_[0]; wr1 = wp_[384]; wr2 = wp_[768]; wr3 = wp_[1152];        \
    }                                                                       \
  }

#define WRITE_STAGE(XH_, XL_, WH_, WL_)                                     \
  {                                                                         \
    unsigned h0_, l0_, h1_, l1_;                                            \
    split2pk(xr0v[0], xr0v[1], h0_, l0_);                                   \
    split2pk(xr0v[2], xr0v[3], h1_, l1_);                                   \
    uint2v hv_ = {h0_, h1_}, lv_ = {l0_, l1_};                              \
    *(uint2v*)&(XH_)[xrow0 * 24 + xgs0] = hv_;                              \
    *(uint2v*)&(XL_)[xrow0 * 24 + xgs0] = lv_;                              \
    if (hasx1) {                                                            \
      split2pk(xr1v[0], xr1v[1], h0_, l0_);                                 \
      split2pk(xr1v[2], xr1v[3], h1_, l1_);                                 \
      uint2v hv2_ = {h0_, h1_}, lv2_ = {l0_, l1_};                          \
      *(uint2v*)&(XH_)[xrow1 * 24 + xgs1] = hv2_;                           \
      *(uint2v*)&(XL_)[xrow1 * 24 + xgs1] = lv2_;                           \
    }                                                                       \
    if (hasw) {                                                             \
      split2pk(wr0, wr1, h0_, l0_);                                         \
      split2pk(wr2, wr3, h1_, l1_);                                         \
      uint2v hw_ = {h0_, h1_}, lw_ = {l0_, l1_};                            \
      *(uint2v*)&(WH_)[wc * 24 + wkgs] = hw_;                               \
      *(uint2v*)&(WL_)[wc * 24 + wkgs] = lw_;                               \
    }                                                                       \
  }

  f32x16 aQ, aK, aV;
#pragma unroll
  for (int r = 0; r < 16; ++r) { aQ[r] = 0.f; aK[r] = 0.f; aV[r] = 0.f; }

  // ---------------- Phase 1: QKV projection, k-chunks of 16 ----------------
  LOAD_STAGE(0);
  for (int kc = 0; kc < 8; ++kc) {
    unsigned short* cXh = (kc & 1) ? Xh1 : Xh0;
    unsigned short* cXl = (kc & 1) ? Xl1 : Xl0;
    unsigned short* cWh = (kc & 1) ? Wh1 : Wh0;
    unsigned short* cWl = (kc & 1) ? Wl1 : Wl0;

    WRITE_STAGE(cXh, cXl, cWh, cWl);   // cvt + LDS write of this chunk
    __syncthreads();                   // writes visible; prior reads retired
    if (kc < 7) LOAD_STAGE(kc + 1);    // issue next chunk's loads NOW

    if (act) {
      const int fo = (half * 8) ^ xsw;
      const int xb = (wv * 32 + l31) * 24 + fo;
      short8 xh = *(const short8*)&cXh[xb];
      short8 xl = *(const short8*)&cXl[xb];
      {  // Q: TRANSPOSED -> A = Wq, B = X
        int wb = l31 * 24 + fo;
        short8 wh8 = *(const short8*)&cWh[wb];
        short8 wl8 = *(const short8*)&cWl[wb];
        aQ = MFMA(wh8, xh, aQ, 0, 0, 0);
        aQ = MFMA(wh8, xl, aQ, 0, 0, 0);
        aQ = MFMA(wl8, xh, aQ, 0, 0, 0);
      }
      {  // K: A = X, B = Wk
        int wb = (32 + l31) * 24 + fo;
        short8 wh8 = *(const short8*)&cWh[wb];
        short8 wl8 = *(const short8*)&cWl[wb];
        aK = MFMA(xh, wh8, aK, 0, 0, 0);
        aK = MFMA(xl, wh8, aK, 0, 0, 0);
        aK = MFMA(xh, wl8, aK, 0, 0, 0);
      }
      {  // V: A = X, B = Wv
        int wb = (64 + l31) * 24 + fo;
        short8 wh8 = *(const short8*)&cWh[wb];
        short8 wl8 = *(const short8*)&cWl[wb];
        aV = MFMA(xh, wh8, aV, 0, 0, 0);
        aV = MFMA(xl, wh8, aV, 0, 0, 0);
        aV = MFMA(xh, wl8, aV, 0, 0, 0);
      }
    }
  }

  __syncthreads();  // all X/W reads done; safe to overwrite with K/V

  // ---- Q^T acc -> phase-2 B-fragment, fully in registers ----
  const float QS = 0.17677669529663687f * 1.4426950408889634f;  // /sqrt(32)*log2e
  uint4v qA = {0, 0, 0, 0}, qB = {0, 0, 0, 0};
  const int swz = ((l31 >> 3) & 3) << 3;
  if (act) {
    unsigned g0 = cvtpk_bf16(aQ[0] * QS, aQ[1] * QS);
    unsigned g1 = cvtpk_bf16(aQ[2] * QS, aQ[3] * QS);
    unsigned g2 = cvtpk_bf16(aQ[4] * QS, aQ[5] * QS);
    unsigned g3 = cvtpk_bf16(aQ[6] * QS, aQ[7] * QS);
    unsigned g4 = cvtpk_bf16(aQ[8] * QS, aQ[9] * QS);
    unsigned g5 = cvtpk_bf16(aQ[10] * QS, aQ[11] * QS);
    unsigned g6 = cvtpk_bf16(aQ[12] * QS, aQ[13] * QS);
    unsigned g7 = cvtpk_bf16(aQ[14] * QS, aQ[15] * QS);
    swap32(g0, g2); swap32(g1, g3); swap32(g4, g6); swap32(g5, g7);
    qA[0] = g0; qA[1] = g1; qA[2] = g2; qA[3] = g3;
    qB[0] = g4; qB[1] = g5; qB[2] = g6; qB[3] = g7;

    // K -> LDS (2-bit XOR col swizzle)
#pragma unroll
    for (int r = 0; r < 16; ++r) {
      int iD = (r & 3) + ((r >> 2) << 3) + (half << 2);
      int cs = l31 ^ ((r >> 2) << 3);
      Kb[(wv * 32 + iD) * 40 + cs] = bf16u(aK[r]);
    }
    // V -> LDS transposed, stride 352, token-swizzled by (d&24)
#pragma unroll
    for (int r = 0; r < 16; r += 2) {
      int j0 = (r & 3) + ((r >> 2) << 3) + (half << 2);
      *(unsigned*)&Vt[l31 * 352 + wv * 32 + (j0 ^ swz)] =
          cvtpk_bf16(aV[r], aV[r + 1]);
    }
  }
  __syncthreads();

  // ---------------- Phase 2: attention ----------------
  if (act) {
    const float* bp = prep + ((size_t)(h * 22 + half) * NP) * 16;
    float* outw = out + (size_t)w * N * DIM + h * DH;
    attend(wv * 32, qA, qB, Kb, Vt, bp, outw, l31, half, swz);
  }
}

// ---------------------------------------------------------------------------
// Kernel 3: out-projection, in-place on d_out, hi/lo split MFMA.
// One block per window, 768 threads (12 waves). Wave wv<=10 owns M-tile wv,
// all 4 N-tiles (acc[4] = 64 AGPR -> 3 waves/SIMD).
// ---------------------------------------------------------------------------
__global__ __launch_bounds__(768, 3) void proj_kernel(
    const float* __restrict__ wout, float* __restrict__ out) {
  const int w = blockIdx.x;
  const int tid = threadIdx.x;
  const int lane = tid & 63, wv = tid >> 6, l31 = lane & 31, half = lane >> 5;
  __shared__ __align__(16) unsigned short lds[38400];     // 76800 B
  unsigned short* Oh = lds;               // [352][40]
  unsigned short* Ol = lds + 14080;
  unsigned short* W2h = lds + 28160;      // [128][40]
  unsigned short* W2l = lds + 33280;
  float* ow = out + (size_t)w * N * DIM;
  const int swz = ((l31 >> 3) & 3) << 3;
  const bool act = (wv < 11);

  f32x16 acc[4];
#pragma unroll
  for (int s = 0; s < 4; ++s)
#pragma unroll
    for (int r = 0; r < 16; ++r) acc[s][r] = 0.f;

  for (int kc = 0; kc < 4; ++kc) {
    __syncthreads();
    // O staging: 2816 quad-groups
#pragma unroll
    for (int p = 0; p < 4; ++p) {
      int idx = tid + p * 768;
      if (idx < 2816) {
        int row = idx >> 3, g = (idx & 7) << 2;
        float4v v = {0.f, 0.f, 0.f, 0.f};
        if (row < N) v = *(const float4v*)(ow + row * DIM + kc * 32 + g);
        unsigned h0, l0, h1, l1;
        split2pk(v[0], v[1], h0, l0);
        split2pk(v[2], v[3], h1, l1);
        uint2v hv = {h0, h1}, lv = {l0, l1};
        int gs = g ^ (((row >> 3) & 3) << 3);
        *(uint2v*)&Oh[row * 40 + gs] = hv;
        *(uint2v*)&Ol[row * 40 + gs] = lv;
      }
    }
    // W2 staging: 1024 quad-jobs (float4 along n, transposed scalar writes)
#pragma unroll
    for (int p = 0; p < 2; ++p) {
      int idx = tid + p * 768;
      if (idx < 1024) {
        int k = idx >> 5, n4 = (idx & 31) << 2;
        float4v v = *(const float4v*)(wout + (size_t)(kc * 32 + k) * DIM + n4);
#pragma unroll
        for (int u = 0; u < 4; ++u) {
          int n = n4 + u;
          int ks = k ^ (((n >> 3) & 3) << 3);
          unsigned short hv = bf16u(v[u]);
          W2h[n * 40 + ks] = hv;
          W2l[n * 40 + ks] =
              bf16u(v[u] - __builtin_bit_cast(float, (unsigned)hv << 16));
        }
      }
    }
    __syncthreads();
    if (act) {
#pragma unroll
      for (int kk = 0; kk < 2; ++kk) {
        int ro = (kk * 16 + half * 8) ^ swz;
        int rb = (wv * 32 + l31) * 40 + ro;
        short8 ah = *(const short8*)&Oh[rb];
        short8 al = *(const short8*)&Ol[rb];
#pragma unroll
        for (int s = 0; s < 4; ++s) {
          int wb = (s * 32 + l31) * 40 + ro;
          short8 bh = *(const short8*)&W2h[wb];
          short8 bl = *(const short8*)&W2l[wb];
          acc[s] = MFMA(ah, bh, acc[s], 0, 0, 0);
          acc[s] = MFMA(ah, bl, acc[s], 0, 0, 0);
          acc[s] = MFMA(al, bh, acc[s], 0, 0, 0);
        }
      }
    }
  }
  if (act) {
#pragma unroll
    for (int s = 0; s < 4; ++s) {
#pragma unroll
      for (int r = 0; r < 16; ++r) {
        int iD = (r & 3) + ((r >> 2) << 3) + (half << 2);
        int i = wv * 32 + iD;
        if (i < N) ow[(size_t)i * DIM + s * 32 + l31] = acc[s][r];
      }
    }
  }
}

// ---------------------------------------------------------------------------
extern "C" void kernel_launch(void* const* d_in, const int* in_sizes, int n_in,
                              void* d_out, int out_size, void* d_ws, size_t ws_size,
                              hipStream_t stream) {
  const float* x     = (const float*)d_in[0];
  const float* wqkv  = (const float*)d_in[1];
  const float* wout  = (const float*)d_in[2];
  const float* table = (const float*)d_in[3];
  const int*   rel   = (const int*)d_in[4];
  float* out  = (float*)d_out;
  float* prep = (float*)d_ws;  // 4*11*2*352*16*4 B = 1.98 MB

  const int B = in_sizes[0] / (N * DIM);  // 512 windows
  const int rows = HEADS * 11 * 2 * NP;   // 30976

  bias_kernel<<<(rows + 255) / 256, 256, 0, stream>>>(table, rel, prep);
  attn_kernel<<<HEADS * B, 768, 0, stream>>>(x, wqkv, prep, out);
  proj_kernel<<<B, 768, 0, stream>>>(wout, out);
}

// Round 14
// 204.838 us; speedup vs baseline: 1.0402x; 1.0402x over previous
//
#include <hip/hip_runtime.h>

#define N 343        // 7*7*7 tokens per window
#define NP 352       // padded to 11 tiles of 32
#define DIM 128
#define HEADS 4
#define DH 32

typedef float  f32x16 __attribute__((ext_vector_type(16)));
typedef float  float4v __attribute__((ext_vector_type(4)));
typedef short  short8 __attribute__((ext_vector_type(8)));
typedef unsigned uint4v __attribute__((ext_vector_type(4)));
typedef unsigned uint2v __attribute__((ext_vector_type(2)));

#define MFMA __builtin_amdgcn_mfma_f32_32x32x16_bf16

// ---- gfx950 packed bf16 convert (RNE) and cross-half swap -----------------
static __device__ __forceinline__ unsigned cvtpk_bf16(float lo, float hi) {
  unsigned r;
  asm("v_cvt_pk_bf16_f32 %0, %1, %2" : "=v"(r) : "v"(lo), "v"(hi));
  return r;
}
static __device__ __forceinline__ void swap32(unsigned &a, unsigned &b) {
  asm("v_permlane32_swap_b32 %0, %1" : "+v"(a), "+v"(b));
}
// native base-2 exponential (v_exp_f32 IS exp2 on CDNA)
static __device__ __forceinline__ float exp2v(float x) {
  float r;
  asm("v_exp_f32 %0, %1" : "=v"(r) : "v"(x));
  return r;
}
static __device__ __forceinline__ unsigned short bf16u(float a) {
  unsigned u = __builtin_bit_cast(unsigned, a);
  unsigned r = u + 0x7fffu + ((u >> 16) & 1u);
  return (unsigned short)(r >> 16);
}
static __device__ __forceinline__ void split2pk(float a, float b,
                                                unsigned &hi, unsigned &lo) {
  hi = cvtpk_bf16(a, b);
  float ra = a - __builtin_bit_cast(float, hi << 16);
  float rb = b - __builtin_bit_cast(float, hi & 0xffff0000u);
  lo = cvtpk_bf16(ra, rb);
}

// ---------------------------------------------------------------------------
// Kernel 1: bias gather pre-permuted into the 32x32 MFMA C-fragment order.
// ---------------------------------------------------------------------------
__global__ __launch_bounds__(256) void bias_kernel(
    const float* __restrict__ table, const int* __restrict__ rel,
    float* __restrict__ prep) {
  int row = blockIdx.x * 256 + threadIdx.x;
  if (row >= HEADS * 11 * 2 * NP) return;
  int i = row % NP;
  int t = row / NP;
  int half = t & 1;
  int tj = t >> 1;
  int jt = tj % 11;
  int h = tj / 11;
  float* dst = prep + (size_t)row * 16;
#pragma unroll
  for (int r = 0; r < 16; ++r) {
    int j = jt * 32 + (r & 3) + ((r >> 2) << 3) + (half << 2);
    float v;
    if (j >= N) v = -1.44e30f;
    else if (i >= N) v = 0.f;
    else v = table[rel[i * N + j] * HEADS + h] * 1.4426950408889634f;
    dst[r] = v;
  }
}

// ---------------------------------------------------------------------------
// Phase-2 flash loop, one 32-row M-tile, Q in registers. R11 semantics
// (max-tracked; no-max failed twice — permanent). SINGLE CHANGE vs R11:
// Vt stride 352 -> 360 u16 (180 dw == 20 mod 32, same conflict-free residue
// class as Kb's 20 dw). V@352 (176 dw == 16 mod 32) put each 8-lane phase
// group on only 2 bank groups -> 4-way conflict on every PV ds_read_b128,
// which accounts for ~1.4e7 conflict cycles (~12% of attn).
// ---------------------------------------------------------------------------
static __device__ __forceinline__ void attend(
    int i0, uint4v qAu, uint4v qBu,
    const unsigned short* __restrict__ Kb, const unsigned short* __restrict__ Vt,
    const float* __restrict__ bp, float* __restrict__ outw,
    int l31, int half, int swz) {
  short8 q0 = __builtin_bit_cast(short8, qAu);
  short8 q1 = __builtin_bit_cast(short8, qBu);
  const float* bpi = bp + (size_t)(i0 + l31) * 16;

  f32x16 O;
#pragma unroll
  for (int r = 0; r < 16; ++r) O[r] = 0.f;
  float m_run = -3.0e38f, l_run = 0.f;

  f32x16 Tn = *(const f32x16*)(bpi);      // prefetch bias tile 0
  for (int jt = 0; jt < 11; ++jt) {
    f32x16 T = Tn;                        // bias IS the MFMA C-input
    if (jt < 10) Tn = *(const f32x16*)(bpi + (size_t)(jt + 1) * 11264);

    const int krow = (jt * 32 + l31) * 40;
    short8 ka0 = *(const short8*)&Kb[krow + ((half * 8) ^ swz)];
    short8 ka1 = *(const short8*)&Kb[krow + ((half * 8 + 16) ^ swz)];
    T = MFMA(ka0, q0, T, 0, 0, 0);
    T = MFMA(ka1, q1, T, 0, 0, 0);

    float m0 = fmaxf(T[0], T[1]),   m1 = fmaxf(T[2], T[3]);
    float m2 = fmaxf(T[4], T[5]),   m3 = fmaxf(T[6], T[7]);
    float m4 = fmaxf(T[8], T[9]),   m5 = fmaxf(T[10], T[11]);
    float m6 = fmaxf(T[12], T[13]), m7 = fmaxf(T[14], T[15]);
    m0 = fmaxf(m0, m1); m2 = fmaxf(m2, m3);
    m4 = fmaxf(m4, m5); m6 = fmaxf(m6, m7);
    m0 = fmaxf(m0, m2); m4 = fmaxf(m4, m6);
    float pm = fmaxf(m0, m4);
    pm = fmaxf(pm, __shfl_xor(pm, 32, 64));

    if (__any(pm > m_run + 11.5f)) {      // deferred-max rescale (rare)
      float nm = fmaxf(m_run, pm);
      float f = exp2v(m_run - nm);
      l_run *= f;
      m_run = nm;
#pragma unroll
      for (int r = 0; r < 16; ++r) {
        int iD = (r & 3) + ((r >> 2) << 3) + (half << 2);
        O[r] *= __shfl(f, iD, 64);
      }
    }

    float p[16];
#pragma unroll
    for (int r = 0; r < 16; ++r) p[r] = exp2v(T[r] - m_run);
    float s0 = (p[0] + p[1]) + (p[2] + p[3]);
    float s1 = (p[4] + p[5]) + (p[6] + p[7]);
    float s2 = (p[8] + p[9]) + (p[10] + p[11]);
    float s3 = (p[12] + p[13]) + (p[14] + p[15]);
    float ps = (s0 + s1) + (s2 + s3);
    l_run += ps + __shfl_xor(ps, 32, 64);

    unsigned k0 = cvtpk_bf16(p[0], p[1]),   k1 = cvtpk_bf16(p[2], p[3]);
    unsigned k2 = cvtpk_bf16(p[4], p[5]),   k3 = cvtpk_bf16(p[6], p[7]);
    unsigned k4 = cvtpk_bf16(p[8], p[9]),   k5 = cvtpk_bf16(p[10], p[11]);
    unsigned k6 = cvtpk_bf16(p[12], p[13]), k7 = cvtpk_bf16(p[14], p[15]);
    swap32(k0, k2); swap32(k1, k3); swap32(k4, k6); swap32(k5, k7);
    uint4v u1 = {k0, k1, k2, k3};
    uint4v u2 = {k4, k5, k6, k7};
    short8 pa1 = __builtin_bit_cast(short8, u1);
    short8 pa2 = __builtin_bit_cast(short8, u2);

    const int vrow = l31 * 360 + jt * 32;
    short8 vb1 = *(const short8*)&Vt[vrow + ((half * 8) ^ swz)];
    short8 vb2 = *(const short8*)&Vt[vrow + ((half * 8 + 16) ^ swz)];
    O = MFMA(pa1, vb1, O, 0, 0, 0);
    O = MFMA(pa2, vb2, O, 0, 0, 0);
  }

  float inv = 1.0f / l_run;
#pragma unroll
  for (int r = 0; r < 16; ++r) {
    int iD = (r & 3) + ((r >> 2) << 3) + (half << 2);
    float invr = __shfl(inv, iD, 64);
    int i = i0 + iD;
    if (i < N) outw[(size_t)i * DIM + l31] = O[r] * invr;
  }
}

// ---------------------------------------------------------------------------
// Kernel 2: fused QKV projection + attention. One block per (window, head),
// 768 threads = 12 waves, one M-tile per wave (wave 11 = staging helper).
// Phase-1 async-STAGE split (T14): chunk kc+1's global loads issue right
// after chunk kc's staging barrier; cvt+LDS-write happen next iteration.
// (R13's double-buffered variant regressed: VGPR 68/LDS 86KB cut occupancy.)
// ---------------------------------------------------------------------------
__global__ __launch_bounds__(768, 3) void attn_kernel(
    const float* __restrict__ x, const float* __restrict__ wqkv,
    const float* __restrict__ prep, float* __restrict__ out) {
  const int b = blockIdx.x;
  const int sw = (b & 7) * ((int)gridDim.x >> 3) + (b >> 3);  // XCD swizzle
  const int h = sw & 3;
  const int w = sw >> 2;
  const int tid = threadIdx.x;
  const int lane = tid & 63;
  const int wv = tid >> 6;        // 0..11
  const int l31 = lane & 31;
  const int half = lane >> 5;

  __shared__ __align__(16) unsigned short lds[25600];   // 51200 B
  unsigned short* Xh = lds;             // [352][24]  (phase 1)
  unsigned short* Xl = lds + 8448;      // [352][24]
  unsigned short* Wh = lds + 16896;     // [96][24]
  unsigned short* Wl = lds + 19200;     // [96][24]
  unsigned short* Kb = lds;             // [352][40]  (phase 2, aliased)
  unsigned short* Vt = lds + 14080;     // [32][360]

  const float* xw = x + (size_t)w * (N * DIM);
  const int xsw = ((l31 >> 3) & 1) << 3;   // 1-bit swizzle for X/W frag reads
  const bool act = (wv < 11);

  // ---- staging geometry (fixed per thread) ----
  const int xrow0 = tid >> 2,  xg0 = (tid & 3) << 2;           // job 0 (all)
  const int idx1  = tid + 768;
  const int xrow1 = idx1 >> 2, xg1 = (idx1 & 3) << 2;          // job 1
  const bool hasx1 = (idx1 < 1408);
  const bool hasw  = (tid < 384);
  const int wc = tid % 96, wkg = (tid / 96) << 2;
  const int wcol = ((wc >> 5) << 7) + h * DH + (wc & 31);
  const int xgs0 = xg0 ^ (((xrow0 >> 3) & 1) << 3);
  const int xgs1 = xg1 ^ (((xrow1 >> 3) & 1) << 3);
  const int wkgs = wkg ^ (((wc >> 3) & 1) << 3);

  float4v xr0v = {0.f, 0.f, 0.f, 0.f}, xr1v = {0.f, 0.f, 0.f, 0.f};
  float wr0 = 0.f, wr1 = 0.f, wr2 = 0.f, wr3 = 0.f;

#define LOAD_STAGE(kc_)                                                     \
  {                                                                         \
    xr0v = *(const float4v*)(xw + xrow0 * DIM + (kc_) * 16 + xg0);          \
    xr1v[0] = 0.f; xr1v[1] = 0.f; xr1v[2] = 0.f; xr1v[3] = 0.f;             \
    if (hasx1 && xrow1 < N)                                                 \
      xr1v = *(const float4v*)(xw + xrow1 * DIM + (kc_) * 16 + xg1);        \
    if (hasw) {                                                             \
      const float* wp_ = wqkv + (size_t)((kc_) * 16 + wkg) * 384 + wcol;    \
      wr0 = wp_[0]; wr1 = wp_[384]; wr2 = wp_[768]; wr3 = wp_[1152];        \
    }                                                                       \
  }

#define WRITE_STAGE()                                                       \
  {                                                                         \
    unsigned h0_, l0_, h1_, l1_;                                            \
    split2pk(xr0v[0], xr0v[1], h0_, l0_);                                   \
    split2pk(xr0v[2], xr0v[3], h1_, l1_);                                   \
    uint2v hv_ = {h0_, h1_}, lv_ = {l0_, l1_};                              \
    *(uint2v*)&Xh[xrow0 * 24 + xgs0] = hv_;                                 \
    *(uint2v*)&Xl[xrow0 * 24 + xgs0] = lv_;                                 \
    if (hasx1) {                                                            \
      split2pk(xr1v[0], xr1v[1], h0_, l0_);                                 \
      split2pk(xr1v[2], xr1v[3], h1_, l1_);                                 \
      uint2v hv2_ = {h0_, h1_}, lv2_ = {l0_, l1_};                          \
      *(uint2v*)&Xh[xrow1 * 24 + xgs1] = hv2_;                              \
      *(uint2v*)&Xl[xrow1 * 24 + xgs1] = lv2_;                              \
    }                                                                       \
    if (hasw) {                                                             \
      split2pk(wr0, wr1, h0_, l0_);                                         \
      split2pk(wr2, wr3, h1_, l1_);                                         \
      uint2v hw_ = {h0_, h1_}, lw_ = {l0_, l1_};                            \
      *(uint2v*)&Wh[wc * 24 + wkgs] = hw_;                                  \
      *(uint2v*)&Wl[wc * 24 + wkgs] = lw_;                                  \
    }                                                                       \
  }

  f32x16 aQ, aK, aV;
#pragma unroll
  for (int r = 0; r < 16; ++r) { aQ[r] = 0.f; aK[r] = 0.f; aV[r] = 0.f; }

  // ---------------- Phase 1: QKV projection, k-chunks of 16 ----------------
  LOAD_STAGE(0);
  for (int kc = 0; kc < 8; ++kc) {
    __syncthreads();            // previous chunk's LDS reads complete
    WRITE_STAGE();              // cvt + LDS write of this chunk
    __syncthreads();            // staging visible
    if (kc < 7) LOAD_STAGE(kc + 1);   // issue next chunk's loads NOW

    if (act) {
      const int fo = (half * 8) ^ xsw;
      const int xb = (wv * 32 + l31) * 24 + fo;
      short8 xh = *(const short8*)&Xh[xb];
      short8 xl = *(const short8*)&Xl[xb];
      {  // Q: TRANSPOSED -> A = Wq, B = X
        int wb = l31 * 24 + fo;
        short8 wh8 = *(const short8*)&Wh[wb];
        short8 wl8 = *(const short8*)&Wl[wb];
        aQ = MFMA(wh8, xh, aQ, 0, 0, 0);
        aQ = MFMA(wh8, xl, aQ, 0, 0, 0);
        aQ = MFMA(wl8, xh, aQ, 0, 0, 0);
      }
      {  // K: A = X, B = Wk
        int wb = (32 + l31) * 24 + fo;
        short8 wh8 = *(const short8*)&Wh[wb];
        short8 wl8 = *(const short8*)&Wl[wb];
        aK = MFMA(xh, wh8, aK, 0, 0, 0);
        aK = MFMA(xl, wh8, aK, 0, 0, 0);
        aK = MFMA(xh, wl8, aK, 0, 0, 0);
      }
      {  // V: A = X, B = Wv
        int wb = (64 + l31) * 24 + fo;
        short8 wh8 = *(const short8*)&Wh[wb];
        short8 wl8 = *(const short8*)&Wl[wb];
        aV = MFMA(xh, wh8, aV, 0, 0, 0);
        aV = MFMA(xl, wh8, aV, 0, 0, 0);
        aV = MFMA(xh, wl8, aV, 0, 0, 0);
      }
    }
  }

  __syncthreads();  // all X/W reads done; safe to overwrite with K/V

  // ---- Q^T acc -> phase-2 B-fragment, fully in registers ----
  const float QS = 0.17677669529663687f * 1.4426950408889634f;  // /sqrt(32)*log2e
  uint4v qA = {0, 0, 0, 0}, qB = {0, 0, 0, 0};
  const int swz = ((l31 >> 3) & 3) << 3;
  if (act) {
    unsigned g0 = cvtpk_bf16(aQ[0] * QS, aQ[1] * QS);
    unsigned g1 = cvtpk_bf16(aQ[2] * QS, aQ[3] * QS);
    unsigned g2 = cvtpk_bf16(aQ[4] * QS, aQ[5] * QS);
    unsigned g3 = cvtpk_bf16(aQ[6] * QS, aQ[7] * QS);
    unsigned g4 = cvtpk_bf16(aQ[8] * QS, aQ[9] * QS);
    unsigned g5 = cvtpk_bf16(aQ[10] * QS, aQ[11] * QS);
    unsigned g6 = cvtpk_bf16(aQ[12] * QS, aQ[13] * QS);
    unsigned g7 = cvtpk_bf16(aQ[14] * QS, aQ[15] * QS);
    swap32(g0, g2); swap32(g1, g3); swap32(g4, g6); swap32(g5, g7);
    qA[0] = g0; qA[1] = g1; qA[2] = g2; qA[3] = g3;
    qB[0] = g4; qB[1] = g5; qB[2] = g6; qB[3] = g7;

    // K -> LDS (2-bit XOR col swizzle)
#pragma unroll
    for (int r = 0; r < 16; ++r) {
      int iD = (r & 3) + ((r >> 2) << 3) + (half << 2);
      int cs = l31 ^ ((r >> 2) << 3);
      Kb[(wv * 32 + iD) * 40 + cs] = bf16u(aK[r]);
    }
    // V -> LDS transposed, stride 360, token-swizzled by (d&24)
#pragma unroll
    for (int r = 0; r < 16; r += 2) {
      int j0 = (r & 3) + ((r >> 2) << 3) + (half << 2);
      *(unsigned*)&Vt[l31 * 360 + wv * 32 + (j0 ^ swz)] =
          cvtpk_bf16(aV[r], aV[r + 1]);
    }
  }
  __syncthreads();

  // ---------------- Phase 2: attention ----------------
  if (act) {
    const float* bp = prep + ((size_t)(h * 22 + half) * NP) * 16;
    float* outw = out + (size_t)w * N * DIM + h * DH;
    attend(wv * 32, qA, qB, Kb, Vt, bp, outw, l31, half, swz);
  }
}

// ---------------------------------------------------------------------------
// Kernel 3: out-projection, in-place on d_out, hi/lo split MFMA.
// One block per window, 768 threads (12 waves). Wave wv<=10 owns M-tile wv,
// all 4 N-tiles (acc[4] = 64 AGPR -> 3 waves/SIMD).
// ---------------------------------------------------------------------------
__global__ __launch_bounds__(768, 3) void proj_kernel(
    const float* __restrict__ wout, float* __restrict__ out) {
  const int w = blockIdx.x;
  const int tid = threadIdx.x;
  const int lane = tid & 63, wv = tid >> 6, l31 = lane & 31, half = lane >> 5;
  __shared__ __align__(16) unsigned short lds[38400];     // 76800 B
  unsigned short* Oh = lds;               // [352][40]
  unsigned short* Ol = lds + 14080;
  unsigned short* W2h = lds + 28160;      // [128][40]
  unsigned short* W2l = lds + 33280;
  float* ow = out + (size_t)w * N * DIM;
  const int swz = ((l31 >> 3) & 3) << 3;
  const bool act = (wv < 11);

  f32x16 acc[4];
#pragma unroll
  for (int s = 0; s < 4; ++s)
#pragma unroll
    for (int r = 0; r < 16; ++r) acc[s][r] = 0.f;

  for (int kc = 0; kc < 4; ++kc) {
    __syncthreads();
    // O staging: 2816 quad-groups
#pragma unroll
    for (int p = 0; p < 4; ++p) {
      int idx = tid + p * 768;
      if (idx < 2816) {
        int row = idx >> 3, g = (idx & 7) << 2;
        float4v v = {0.f, 0.f, 0.f, 0.f};
        if (row < N) v = *(const float4v*)(ow + row * DIM + kc * 32 + g);
        unsigned h0, l0, h1, l1;
        split2pk(v[0], v[1], h0, l0);
        split2pk(v[2], v[3], h1, l1);
        uint2v hv = {h0, h1}, lv = {l0, l1};
        int gs = g ^ (((row >> 3) & 3) << 3);
        *(uint2v*)&Oh[row * 40 + gs] = hv;
        *(uint2v*)&Ol[row * 40 + gs] = lv;
      }
    }
    // W2 staging: 1024 quad-jobs (float4 along n, transposed scalar writes)
#pragma unroll
    for (int p = 0; p < 2; ++p) {
      int idx = tid + p * 768;
      if (idx < 1024) {
        int k = idx >> 5, n4 = (idx & 31) << 2;
        float4v v = *(const float4v*)(wout + (size_t)(kc * 32 + k) * DIM + n4);
#pragma unroll
        for (int u = 0; u < 4; ++u) {
          int n = n4 + u;
          int ks = k ^ (((n >> 3) & 3) << 3);
          unsigned short hv = bf16u(v[u]);
          W2h[n * 40 + ks] = hv;
          W2l[n * 40 + ks] =
              bf16u(v[u] - __builtin_bit_cast(float, (unsigned)hv << 16));
        }
      }
    }
    __syncthreads();
    if (act) {
#pragma unroll
      for (int kk = 0; kk < 2; ++kk) {
        int ro = (kk * 16 + half * 8) ^ swz;
        int rb = (wv * 32 + l31) * 40 + ro;
        short8 ah = *(const short8*)&Oh[rb];
        short8 al = *(const short8*)&Ol[rb];
#pragma unroll
        for (int s = 0; s < 4; ++s) {
          int wb = (s * 32 + l31) * 40 + ro;
          short8 bh = *(const short8*)&W2h[wb];
          short8 bl = *(const short8*)&W2l[wb];
          acc[s] = MFMA(ah, bh, acc[s], 0, 0, 0);
          acc[s] = MFMA(ah, bl, acc[s], 0, 0, 0);
          acc[s] = MFMA(al, bh, acc[s], 0, 0, 0);
        }
      }
    }
  }
  if (act) {
#pragma unroll
    for (int s = 0; s < 4; ++s) {
#pragma unroll
      for (int r = 0; r < 16; ++r) {
        int iD = (r & 3) + ((r >> 2) << 3) + (half << 2);
        int i = wv * 32 + iD;
        if (i < N) ow[(size_t)i * DIM + s * 32 + l31] = acc[s][r];
      }
    }
  }
}

// ---------------------------------------------------------------------------
extern "C" void kernel_launch(void* const* d_in, const int* in_sizes, int n_in,
                              void* d_out, int out_size, void* d_ws, size_t ws_size,
                              hipStream_t stream) {
  const float* x     = (const float*)d_in[0];
  const float* wqkv  = (const float*)d_in[1];
  const float* wout  = (const float*)d_in[2];
  const float* table = (const float*)d_in[3];
  const int*   rel   = (const int*)d_in[4];
  float* out  = (float*)d_out;
  float* prep = (float*)d_ws;  // 4*11*2*352*16*4 B = 1.98 MB

  const int B = in_sizes[0] / (N * DIM);  // 512 windows
  const int rows = HEADS * 11 * 2 * NP;   // 30976

  bias_kernel<<<(rows + 255) / 256, 256, 0, stream>>>(table, rel, prep);
  attn_kernel<<<HEADS * B, 768, 0, stream>>>(x, wqkv, prep, out);
  proj_kernel<<<B, 768, 0, stream>>>(wout, out);
}

// Round 15
// 204.280 us; speedup vs baseline: 1.0431x; 1.0027x over previous
//
#include <hip/hip_runtime.h>

#define N 343        // 7*7*7 tokens per window
#define NP 352       // padded to 11 tiles of 32
#define DIM 128
#define HEADS 4
#define DH 32

typedef float  f32x16 __attribute__((ext_vector_type(16)));
typedef float  float4v __attribute__((ext_vector_type(4)));
typedef short  short8 __attribute__((ext_vector_type(8)));
typedef unsigned uint4v __attribute__((ext_vector_type(4)));
typedef unsigned uint2v __attribute__((ext_vector_type(2)));

#define MFMA __builtin_amdgcn_mfma_f32_32x32x16_bf16

// ---- gfx950 packed bf16 convert (RNE) and cross-half swap -----------------
static __device__ __forceinline__ unsigned cvtpk_bf16(float lo, float hi) {
  unsigned r;
  asm("v_cvt_pk_bf16_f32 %0, %1, %2" : "=v"(r) : "v"(lo), "v"(hi));
  return r;
}
static __device__ __forceinline__ void swap32(unsigned &a, unsigned &b) {
  asm("v_permlane32_swap_b32 %0, %1" : "+v"(a), "+v"(b));
}
// native base-2 exponential (v_exp_f32 IS exp2 on CDNA)
static __device__ __forceinline__ float exp2v(float x) {
  float r;
  asm("v_exp_f32 %0, %1" : "=v"(r) : "v"(x));
  return r;
}
static __device__ __forceinline__ unsigned short bf16u(float a) {
  unsigned u = __builtin_bit_cast(unsigned, a);
  unsigned r = u + 0x7fffu + ((u >> 16) & 1u);
  return (unsigned short)(r >> 16);
}
static __device__ __forceinline__ void split2pk(float a, float b,
                                                unsigned &hi, unsigned &lo) {
  hi = cvtpk_bf16(a, b);
  float ra = a - __builtin_bit_cast(float, hi << 16);
  float rb = b - __builtin_bit_cast(float, hi & 0xffff0000u);
  lo = cvtpk_bf16(ra, rb);
}

// ---------------------------------------------------------------------------
// Kernel 1: bias gather pre-permuted into the 32x32 MFMA C-fragment order.
// ---------------------------------------------------------------------------
__global__ __launch_bounds__(256) void bias_kernel(
    const float* __restrict__ table, const int* __restrict__ rel,
    float* __restrict__ prep) {
  int row = blockIdx.x * 256 + threadIdx.x;
  if (row >= HEADS * 11 * 2 * NP) return;
  int i = row % NP;
  int t = row / NP;
  int half = t & 1;
  int tj = t >> 1;
  int jt = tj % 11;
  int h = tj / 11;
  float* dst = prep + (size_t)row * 16;
#pragma unroll
  for (int r = 0; r < 16; ++r) {
    int j = jt * 32 + (r & 3) + ((r >> 2) << 3) + (half << 2);
    float v;
    if (j >= N) v = -1.44e30f;
    else if (i >= N) v = 0.f;
    else v = table[rel[i * N + j] * HEADS + h] * 1.4426950408889634f;
    dst[r] = v;
  }
}

// ---------------------------------------------------------------------------
// Phase-2 flash loop, one 32-row M-tile, Q in registers. R11/R14 semantics
// (max-tracked; no-max failed twice — permanent). SINGLE CHANGE vs R14:
// T5 s_setprio(1) around the MFMA pairs. Phase-2 waves are barrier-free and
// sit at different jt phases on the same SIMD -> priority lets the MFMA-
// entering wave preempt staging/VALU waves (the documented attn-positive
// case; phase-1 is barrier-locked so it stays unprioritized).
// Kb: [352][40] col-swizzled by (row&24). Vt: [32][360] token-swizzled
// (d&24). Conflicts at this level are NOT on the critical path (R11 vs R14:
// 1.45e7 vs 1.85e7 conflict cyc, identical dur) — stop tuning strides.
// ---------------------------------------------------------------------------
static __device__ __forceinline__ void attend(
    int i0, uint4v qAu, uint4v qBu,
    const unsigned short* __restrict__ Kb, const unsigned short* __restrict__ Vt,
    const float* __restrict__ bp, float* __restrict__ outw,
    int l31, int half, int swz) {
  short8 q0 = __builtin_bit_cast(short8, qAu);
  short8 q1 = __builtin_bit_cast(short8, qBu);
  const float* bpi = bp + (size_t)(i0 + l31) * 16;

  f32x16 O;
#pragma unroll
  for (int r = 0; r < 16; ++r) O[r] = 0.f;
  float m_run = -3.0e38f, l_run = 0.f;

  f32x16 Tn = *(const f32x16*)(bpi);      // prefetch bias tile 0
  for (int jt = 0; jt < 11; ++jt) {
    f32x16 T = Tn;                        // bias IS the MFMA C-input
    if (jt < 10) Tn = *(const f32x16*)(bpi + (size_t)(jt + 1) * 11264);

    const int krow = (jt * 32 + l31) * 40;
    short8 ka0 = *(const short8*)&Kb[krow + ((half * 8) ^ swz)];
    short8 ka1 = *(const short8*)&Kb[krow + ((half * 8 + 16) ^ swz)];
    __builtin_amdgcn_s_setprio(1);
    T = MFMA(ka0, q0, T, 0, 0, 0);
    T = MFMA(ka1, q1, T, 0, 0, 0);
    __builtin_amdgcn_s_setprio(0);

    float m0 = fmaxf(T[0], T[1]),   m1 = fmaxf(T[2], T[3]);
    float m2 = fmaxf(T[4], T[5]),   m3 = fmaxf(T[6], T[7]);
    float m4 = fmaxf(T[8], T[9]),   m5 = fmaxf(T[10], T[11]);
    float m6 = fmaxf(T[12], T[13]), m7 = fmaxf(T[14], T[15]);
    m0 = fmaxf(m0, m1); m2 = fmaxf(m2, m3);
    m4 = fmaxf(m4, m5); m6 = fmaxf(m6, m7);
    m0 = fmaxf(m0, m2); m4 = fmaxf(m4, m6);
    float pm = fmaxf(m0, m4);
    pm = fmaxf(pm, __shfl_xor(pm, 32, 64));

    if (__any(pm > m_run + 11.5f)) {      // deferred-max rescale (rare)
      float nm = fmaxf(m_run, pm);
      float f = exp2v(m_run - nm);
      l_run *= f;
      m_run = nm;
#pragma unroll
      for (int r = 0; r < 16; ++r) {
        int iD = (r & 3) + ((r >> 2) << 3) + (half << 2);
        O[r] *= __shfl(f, iD, 64);
      }
    }

    float p[16];
#pragma unroll
    for (int r = 0; r < 16; ++r) p[r] = exp2v(T[r] - m_run);
    float s0 = (p[0] + p[1]) + (p[2] + p[3]);
    float s1 = (p[4] + p[5]) + (p[6] + p[7]);
    float s2 = (p[8] + p[9]) + (p[10] + p[11]);
    float s3 = (p[12] + p[13]) + (p[14] + p[15]);
    float ps = (s0 + s1) + (s2 + s3);
    l_run += ps + __shfl_xor(ps, 32, 64);

    unsigned k0 = cvtpk_bf16(p[0], p[1]),   k1 = cvtpk_bf16(p[2], p[3]);
    unsigned k2 = cvtpk_bf16(p[4], p[5]),   k3 = cvtpk_bf16(p[6], p[7]);
    unsigned k4 = cvtpk_bf16(p[8], p[9]),   k5 = cvtpk_bf16(p[10], p[11]);
    unsigned k6 = cvtpk_bf16(p[12], p[13]), k7 = cvtpk_bf16(p[14], p[15]);
    swap32(k0, k2); swap32(k1, k3); swap32(k4, k6); swap32(k5, k7);
    uint4v u1 = {k0, k1, k2, k3};
    uint4v u2 = {k4, k5, k6, k7};
    short8 pa1 = __builtin_bit_cast(short8, u1);
    short8 pa2 = __builtin_bit_cast(short8, u2);

    const int vrow = l31 * 360 + jt * 32;
    short8 vb1 = *(const short8*)&Vt[vrow + ((half * 8) ^ swz)];
    short8 vb2 = *(const short8*)&Vt[vrow + ((half * 8 + 16) ^ swz)];
    __builtin_amdgcn_s_setprio(1);
    O = MFMA(pa1, vb1, O, 0, 0, 0);
    O = MFMA(pa2, vb2, O, 0, 0, 0);
    __builtin_amdgcn_s_setprio(0);
  }

  float inv = 1.0f / l_run;
#pragma unroll
  for (int r = 0; r < 16; ++r) {
    int iD = (r & 3) + ((r >> 2) << 3) + (half << 2);
    float invr = __shfl(inv, iD, 64);
    int i = i0 + iD;
    if (i < N) outw[(size_t)i * DIM + l31] = O[r] * invr;
  }
}

// ---------------------------------------------------------------------------
// Kernel 2: fused QKV projection + attention. One block per (window, head),
// 768 threads = 12 waves, one M-tile per wave (wave 11 = staging helper).
// Phase-1 async-STAGE split (T14): chunk kc+1's global loads issue right
// after chunk kc's staging barrier; cvt+LDS-write happen next iteration.
// ---------------------------------------------------------------------------
__global__ __launch_bounds__(768, 3) void attn_kernel(
    const float* __restrict__ x, const float* __restrict__ wqkv,
    const float* __restrict__ prep, float* __restrict__ out) {
  const int b = blockIdx.x;
  const int sw = (b & 7) * ((int)gridDim.x >> 3) + (b >> 3);  // XCD swizzle
  const int h = sw & 3;
  const int w = sw >> 2;
  const int tid = threadIdx.x;
  const int lane = tid & 63;
  const int wv = tid >> 6;        // 0..11
  const int l31 = lane & 31;
  const int half = lane >> 5;

  __shared__ __align__(16) unsigned short lds[25600];   // 51200 B
  unsigned short* Xh = lds;             // [352][24]  (phase 1)
  unsigned short* Xl = lds + 8448;      // [352][24]
  unsigned short* Wh = lds + 16896;     // [96][24]
  unsigned short* Wl = lds + 19200;     // [96][24]
  unsigned short* Kb = lds;             // [352][40]  (phase 2, aliased)
  unsigned short* Vt = lds + 14080;     // [32][360]

  const float* xw = x + (size_t)w * (N * DIM);
  const int xsw = ((l31 >> 3) & 1) << 3;   // 1-bit swizzle for X/W frag reads
  const bool act = (wv < 11);

  // ---- staging geometry (fixed per thread) ----
  const int xrow0 = tid >> 2,  xg0 = (tid & 3) << 2;           // job 0 (all)
  const int idx1  = tid + 768;
  const int xrow1 = idx1 >> 2, xg1 = (idx1 & 3) << 2;          // job 1
  const bool hasx1 = (idx1 < 1408);
  const bool hasw  = (tid < 384);
  const int wc = tid % 96, wkg = (tid / 96) << 2;
  const int wcol = ((wc >> 5) << 7) + h * DH + (wc & 31);
  const int xgs0 = xg0 ^ (((xrow0 >> 3) & 1) << 3);
  const int xgs1 = xg1 ^ (((xrow1 >> 3) & 1) << 3);
  const int wkgs = wkg ^ (((wc >> 3) & 1) << 3);

  float4v xr0v = {0.f, 0.f, 0.f, 0.f}, xr1v = {0.f, 0.f, 0.f, 0.f};
  float wr0 = 0.f, wr1 = 0.f, wr2 = 0.f, wr3 = 0.f;

#define LOAD_STAGE(kc_)                                                     \
  {                                                                         \
    xr0v = *(const float4v*)(xw + xrow0 * DIM + (kc_) * 16 + xg0);          \
    xr1v[0] = 0.f; xr1v[1] = 0.f; xr1v[2] = 0.f; xr1v[3] = 0.f;             \
    if (hasx1 && xrow1 < N)                                                 \
      xr1v = *(const float4v*)(xw + xrow1 * DIM + (kc_) * 16 + xg1);        \
    if (hasw) {                                                             \
      const float* wp_ = wqkv + (size_t)((kc_) * 16 + wkg) * 384 + wcol;    \
      wr0 = wp_[0]; wr1 = wp_[384]; wr2 = wp_[768]; wr3 = wp_[1152];        \
    }                                                                       \
  }

#define WRITE_STAGE()                                                       \
  {                                                                         \
    unsigned h0_, l0_, h1_, l1_;                                            \
    split2pk(xr0v[0], xr0v[1], h0_, l0_);                                   \
    split2pk(xr0v[2], xr0v[3], h1_, l1_);                                   \
    uint2v hv_ = {h0_, h1_}, lv_ = {l0_, l1_};                              \
    *(uint2v*)&Xh[xrow0 * 24 + xgs0] = hv_;                                 \
    *(uint2v*)&Xl[xrow0 * 24 + xgs0] = lv_;                                 \
    if (hasx1) {                                                            \
      split2pk(xr1v[0], xr1v[1], h0_, l0_);                                 \
      split2pk(xr1v[2], xr1v[3], h1_, l1_);                                 \
      uint2v hv2_ = {h0_, h1_}, lv2_ = {l0_, l1_};                          \
      *(uint2v*)&Xh[xrow1 * 24 + xgs1] = hv2_;                              \
      *(uint2v*)&Xl[xrow1 * 24 + xgs1] = lv2_;                              \
    }                                                                       \
    if (hasw) {                                                             \
      split2pk(wr0, wr1, h0_, l0_);                                         \
      split2pk(wr2, wr3, h1_, l1_);                                         \
      uint2v hw_ = {h0_, h1_}, lw_ = {l0_, l1_};                            \
      *(uint2v*)&Wh[wc * 24 + wkgs] = hw_;                                  \
      *(uint2v*)&Wl[wc * 24 + wkgs] = lw_;                                  \
    }                                                                       \
  }

  f32x16 aQ, aK, aV;
#pragma unroll
  for (int r = 0; r < 16; ++r) { aQ[r] = 0.f; aK[r] = 0.f; aV[r] = 0.f; }

  // ---------------- Phase 1: QKV projection, k-chunks of 16 ----------------
  LOAD_STAGE(0);
  for (int kc = 0; kc < 8; ++kc) {
    __syncthreads();            // previous chunk's LDS reads complete
    WRITE_STAGE();              // cvt + LDS write of this chunk
    __syncthreads();            // staging visible
    if (kc < 7) LOAD_STAGE(kc + 1);   // issue next chunk's loads NOW

    if (act) {
      const int fo = (half * 8) ^ xsw;
      const int xb = (wv * 32 + l31) * 24 + fo;
      short8 xh = *(const short8*)&Xh[xb];
      short8 xl = *(const short8*)&Xl[xb];
      {  // Q: TRANSPOSED -> A = Wq, B = X
        int wb = l31 * 24 + fo;
        short8 wh8 = *(const short8*)&Wh[wb];
        short8 wl8 = *(const short8*)&Wl[wb];
        aQ = MFMA(wh8, xh, aQ, 0, 0, 0);
        aQ = MFMA(wh8, xl, aQ, 0, 0, 0);
        aQ = MFMA(wl8, xh, aQ, 0, 0, 0);
      }
      {  // K: A = X, B = Wk
        int wb = (32 + l31) * 24 + fo;
        short8 wh8 = *(const short8*)&Wh[wb];
        short8 wl8 = *(const short8*)&Wl[wb];
        aK = MFMA(xh, wh8, aK, 0, 0, 0);
        aK = MFMA(xl, wh8, aK, 0, 0, 0);
        aK = MFMA(xh, wl8, aK, 0, 0, 0);
      }
      {  // V: A = X, B = Wv
        int wb = (64 + l31) * 24 + fo;
        short8 wh8 = *(const short8*)&Wh[wb];
        short8 wl8 = *(const short8*)&Wl[wb];
        aV = MFMA(xh, wh8, aV, 0, 0, 0);
        aV = MFMA(xl, wh8, aV, 0, 0, 0);
        aV = MFMA(xh, wl8, aV, 0, 0, 0);
      }
    }
  }

  __syncthreads();  // all X/W reads done; safe to overwrite with K/V

  // ---- Q^T acc -> phase-2 B-fragment, fully in registers ----
  const float QS = 0.17677669529663687f * 1.4426950408889634f;  // /sqrt(32)*log2e
  uint4v qA = {0, 0, 0, 0}, qB = {0, 0, 0, 0};
  const int swz = ((l31 >> 3) & 3) << 3;
  if (act) {
    unsigned g0 = cvtpk_bf16(aQ[0] * QS, aQ[1] * QS);
    unsigned g1 = cvtpk_bf16(aQ[2] * QS, aQ[3] * QS);
    unsigned g2 = cvtpk_bf16(aQ[4] * QS, aQ[5] * QS);
    unsigned g3 = cvtpk_bf16(aQ[6] * QS, aQ[7] * QS);
    unsigned g4 = cvtpk_bf16(aQ[8] * QS, aQ[9] * QS);
    unsigned g5 = cvtpk_bf16(aQ[10] * QS, aQ[11] * QS);
    unsigned g6 = cvtpk_bf16(aQ[12] * QS, aQ[13] * QS);
    unsigned g7 = cvtpk_bf16(aQ[14] * QS, aQ[15] * QS);
    swap32(g0, g2); swap32(g1, g3); swap32(g4, g6); swap32(g5, g7);
    qA[0] = g0; qA[1] = g1; qA[2] = g2; qA[3] = g3;
    qB[0] = g4; qB[1] = g5; qB[2] = g6; qB[3] = g7;

    // K -> LDS (2-bit XOR col swizzle)
#pragma unroll
    for (int r = 0; r < 16; ++r) {
      int iD = (r & 3) + ((r >> 2) << 3) + (half << 2);
      int cs = l31 ^ ((r >> 2) << 3);
      Kb[(wv * 32 + iD) * 40 + cs] = bf16u(aK[r]);
    }
    // V -> LDS transposed, stride 360, token-swizzled by (d&24)
#pragma unroll
    for (int r = 0; r < 16; r += 2) {
      int j0 = (r & 3) + ((r >> 2) << 3) + (half << 2);
      *(unsigned*)&Vt[l31 * 360 + wv * 32 + (j0 ^ swz)] =
          cvtpk_bf16(aV[r], aV[r + 1]);
    }
  }
  __syncthreads();

  // ---------------- Phase 2: attention ----------------
  if (act) {
    const float* bp = prep + ((size_t)(h * 22 + half) * NP) * 16;
    float* outw = out + (size_t)w * N * DIM + h * DH;
    attend(wv * 32, qA, qB, Kb, Vt, bp, outw, l31, half, swz);
  }
}

// ---------------------------------------------------------------------------
// Kernel 3: out-projection, in-place on d_out, hi/lo split MFMA.
// One block per window, 768 threads (12 waves). Wave wv<=10 owns M-tile wv,
// all 4 N-tiles (acc[4] = 64 AGPR -> 3 waves/SIMD).
// ---------------------------------------------------------------------------
__global__ __launch_bounds__(768, 3) void proj_kernel(
    const float* __restrict__ wout, float* __restrict__ out) {
  const int w = blockIdx.x;
  const int tid = threadIdx.x;
  const int lane = tid & 63, wv = tid >> 6, l31 = lane & 31, half = lane >> 5;
  __shared__ __align__(16) unsigned short lds[38400];     // 76800 B
  unsigned short* Oh = lds;               // [352][40]
  unsigned short* Ol = lds + 14080;
  unsigned short* W2h = lds + 28160;      // [128][40]
  unsigned short* W2l = lds + 33280;
  float* ow = out + (size_t)w * N * DIM;
  const int swz = ((l31 >> 3) & 3) << 3;
  const bool act = (wv < 11);

  f32x16 acc[4];
#pragma unroll
  for (int s = 0; s < 4; ++s)
#pragma unroll
    for (int r = 0; r < 16; ++r) acc[s][r] = 0.f;

  for (int kc = 0; kc < 4; ++kc) {
    __syncthreads();
    // O staging: 2816 quad-groups
#pragma unroll
    for (int p = 0; p < 4; ++p) {
      int idx = tid + p * 768;
      if (idx < 2816) {
        int row = idx >> 3, g = (idx & 7) << 2;
        float4v v = {0.f, 0.f, 0.f, 0.f};
        if (row < N) v = *(const float4v*)(ow + row * DIM + kc * 32 + g);
        unsigned h0, l0, h1, l1;
        split2pk(v[0], v[1], h0, l0);
        split2pk(v[2], v[3], h1, l1);
        uint2v hv = {h0, h1}, lv = {l0, l1};
        int gs = g ^ (((row >> 3) & 3) << 3);
        *(uint2v*)&Oh[row * 40 + gs] = hv;
        *(uint2v*)&Ol[row * 40 + gs] = lv;
      }
    }
    // W2 staging: 1024 quad-jobs (float4 along n, transposed scalar writes)
#pragma unroll
    for (int p = 0; p < 2; ++p) {
      int idx = tid + p * 768;
      if (idx < 1024) {
        int k = idx >> 5, n4 = (idx & 31) << 2;
        float4v v = *(const float4v*)(wout + (size_t)(kc * 32 + k) * DIM + n4);
#pragma unroll
        for (int u = 0; u < 4; ++u) {
          int n = n4 + u;
          int ks = k ^ (((n >> 3) & 3) << 3);
          unsigned short hv = bf16u(v[u]);
          W2h[n * 40 + ks] = hv;
          W2l[n * 40 + ks] =
              bf16u(v[u] - __builtin_bit_cast(float, (unsigned)hv << 16));
        }
      }
    }
    __syncthreads();
    if (act) {
#pragma unroll
      for (int kk = 0; kk < 2; ++kk) {
        int ro = (kk * 16 + half * 8) ^ swz;
        int rb = (wv * 32 + l31) * 40 + ro;
        short8 ah = *(const short8*)&Oh[rb];
        short8 al = *(const short8*)&Ol[rb];
#pragma unroll
        for (int s = 0; s < 4; ++s) {
          int wb = (s * 32 + l31) * 40 + ro;
          short8 bh = *(const short8*)&W2h[wb];
          short8 bl = *(const short8*)&W2l[wb];
          acc[s] = MFMA(ah, bh, acc[s], 0, 0, 0);
          acc[s] = MFMA(ah, bl, acc[s], 0, 0, 0);
          acc[s] = MFMA(al, bh, acc[s], 0, 0, 0);
        }
      }
    }
  }
  if (act) {
#pragma unroll
    for (int s = 0; s < 4; ++s) {
#pragma unroll
      for (int r = 0; r < 16; ++r) {
        int iD = (r & 3) + ((r >> 2) << 3) + (half << 2);
        int i = wv * 32 + iD;
        if (i < N) ow[(size_t)i * DIM + s * 32 + l31] = acc[s][r];
      }
    }
  }
}

// ---------------------------------------------------------------------------
extern "C" void kernel_launch(void* const* d_in, const int* in_sizes, int n_in,
                              void* d_out, int out_size, void* d_ws, size_t ws_size,
                              hipStream_t stream) {
  const float* x     = (const float*)d_in[0];
  const float* wqkv  = (const float*)d_in[1];
  const float* wout  = (const float*)d_in[2];
  const float* table = (const float*)d_in[3];
  const int*   rel   = (const int*)d_in[4];
  float* out  = (float*)d_out;
  float* prep = (float*)d_ws;  // 4*11*2*352*16*4 B = 1.98 MB

  const int B = in_sizes[0] / (N * DIM);  // 512 windows
  const int rows = HEADS * 11 * 2 * NP;   // 30976

  bias_kernel<<<(rows + 255) / 256, 256, 0, stream>>>(table, rel, prep);
  attn_kernel<<<HEADS * B, 768, 0, stream>>>(x, wqkv, prep, out);
  proj_kernel<<<B, 768, 0, stream>>>(wout, out);
}

// Round 16
// 191.838 us; speedup vs baseline: 1.1107x; 1.0649x over previous
//
#include <hip/hip_runtime.h>

#define N 343        // 7*7*7 tokens per window
#define NP 352       // padded to 11 tiles of 32
#define DIM 128
#define HEADS 4
#define DH 32

typedef float  f32x16 __attribute__((ext_vector_type(16)));
typedef float  float4v __attribute__((ext_vector_type(4)));
typedef short  short8 __attribute__((ext_vector_type(8)));
typedef unsigned uint4v __attribute__((ext_vector_type(4)));
typedef unsigned uint2v __attribute__((ext_vector_type(2)));

#define MFMA __builtin_amdgcn_mfma_f32_32x32x16_bf16

// ---- gfx950 packed bf16 convert (RNE) and cross-half swap -----------------
static __device__ __forceinline__ unsigned cvtpk_bf16(float lo, float hi) {
  unsigned r;
  asm("v_cvt_pk_bf16_f32 %0, %1, %2" : "=v"(r) : "v"(lo), "v"(hi));
  return r;
}
static __device__ __forceinline__ void swap32(unsigned &a, unsigned &b) {
  asm("v_permlane32_swap_b32 %0, %1" : "+v"(a), "+v"(b));
}
// native base-2 exponential (v_exp_f32 IS exp2 on CDNA)
static __device__ __forceinline__ float exp2v(float x) {
  float r;
  asm("v_exp_f32 %0, %1" : "=v"(r) : "v"(x));
  return r;
}
static __device__ __forceinline__ unsigned short bf16u(float a) {
  unsigned u = __builtin_bit_cast(unsigned, a);
  unsigned r = u + 0x7fffu + ((u >> 16) & 1u);
  return (unsigned short)(r >> 16);
}
static __device__ __forceinline__ void split2pk(float a, float b,
                                                unsigned &hi, unsigned &lo) {
  hi = cvtpk_bf16(a, b);
  float ra = a - __builtin_bit_cast(float, hi << 16);
  float rb = b - __builtin_bit_cast(float, hi & 0xffff0000u);
  lo = cvtpk_bf16(ra, rb);
}

// ---------------------------------------------------------------------------
// Kernel 1: bias gather pre-permuted into the 32x32 MFMA C-fragment order.
// ---------------------------------------------------------------------------
__global__ __launch_bounds__(256) void bias_kernel(
    const float* __restrict__ table, const int* __restrict__ rel,
    float* __restrict__ prep) {
  int row = blockIdx.x * 256 + threadIdx.x;
  if (row >= HEADS * 11 * 2 * NP) return;
  int i = row % NP;
  int t = row / NP;
  int half = t & 1;
  int tj = t >> 1;
  int jt = tj % 11;
  int h = tj / 11;
  float* dst = prep + (size_t)row * 16;
#pragma unroll
  for (int r = 0; r < 16; ++r) {
    int j = jt * 32 + (r & 3) + ((r >> 2) << 3) + (half << 2);
    float v;
    if (j >= N) v = -1.44e30f;
    else if (i >= N) v = 0.f;
    else v = table[rel[i * N + j] * HEADS + h] * 1.4426950408889634f;
    dst[r] = v;
  }
}

// ---------------------------------------------------------------------------
// Phase-2 flash loop, one 32-row M-tile, Q in registers. R11/R14 semantics
// (max-tracked; no-max failed twice — permanent; setprio measured neutral
// and removed). Kb: [352][40] col-swizzled by (row&24). Vt: [32][360]
// token-swizzled (d&24). Bank conflicts at this level are NOT on the
// critical path (R11 vs R14 A/B: 1.45e7 vs 1.85e7 cyc, identical dur).
// ---------------------------------------------------------------------------
static __device__ __forceinline__ void attend(
    int i0, uint4v qAu, uint4v qBu,
    const unsigned short* __restrict__ Kb, const unsigned short* __restrict__ Vt,
    const float* __restrict__ bp, float* __restrict__ outw,
    int l31, int half, int swz) {
  short8 q0 = __builtin_bit_cast(short8, qAu);
  short8 q1 = __builtin_bit_cast(short8, qBu);
  const float* bpi = bp + (size_t)(i0 + l31) * 16;

  f32x16 O;
#pragma unroll
  for (int r = 0; r < 16; ++r) O[r] = 0.f;
  float m_run = -3.0e38f, l_run = 0.f;

  f32x16 Tn = *(const f32x16*)(bpi);      // prefetch bias tile 0
  for (int jt = 0; jt < 11; ++jt) {
    f32x16 T = Tn;                        // bias IS the MFMA C-input
    if (jt < 10) Tn = *(const f32x16*)(bpi + (size_t)(jt + 1) * 11264);

    const int krow = (jt * 32 + l31) * 40;
    short8 ka0 = *(const short8*)&Kb[krow + ((half * 8) ^ swz)];
    short8 ka1 = *(const short8*)&Kb[krow + ((half * 8 + 16) ^ swz)];
    T = MFMA(ka0, q0, T, 0, 0, 0);
    T = MFMA(ka1, q1, T, 0, 0, 0);

    float m0 = fmaxf(T[0], T[1]),   m1 = fmaxf(T[2], T[3]);
    float m2 = fmaxf(T[4], T[5]),   m3 = fmaxf(T[6], T[7]);
    float m4 = fmaxf(T[8], T[9]),   m5 = fmaxf(T[10], T[11]);
    float m6 = fmaxf(T[12], T[13]), m7 = fmaxf(T[14], T[15]);
    m0 = fmaxf(m0, m1); m2 = fmaxf(m2, m3);
    m4 = fmaxf(m4, m5); m6 = fmaxf(m6, m7);
    m0 = fmaxf(m0, m2); m4 = fmaxf(m4, m6);
    float pm = fmaxf(m0, m4);
    pm = fmaxf(pm, __shfl_xor(pm, 32, 64));

    if (__any(pm > m_run + 11.5f)) {      // deferred-max rescale (rare)
      float nm = fmaxf(m_run, pm);
      float f = exp2v(m_run - nm);
      l_run *= f;
      m_run = nm;
#pragma unroll
      for (int r = 0; r < 16; ++r) {
        int iD = (r & 3) + ((r >> 2) << 3) + (half << 2);
        O[r] *= __shfl(f, iD, 64);
      }
    }

    float p[16];
#pragma unroll
    for (int r = 0; r < 16; ++r) p[r] = exp2v(T[r] - m_run);
    float s0 = (p[0] + p[1]) + (p[2] + p[3]);
    float s1 = (p[4] + p[5]) + (p[6] + p[7]);
    float s2 = (p[8] + p[9]) + (p[10] + p[11]);
    float s3 = (p[12] + p[13]) + (p[14] + p[15]);
    float ps = (s0 + s1) + (s2 + s3);
    l_run += ps + __shfl_xor(ps, 32, 64);

    unsigned k0 = cvtpk_bf16(p[0], p[1]),   k1 = cvtpk_bf16(p[2], p[3]);
    unsigned k2 = cvtpk_bf16(p[4], p[5]),   k3 = cvtpk_bf16(p[6], p[7]);
    unsigned k4 = cvtpk_bf16(p[8], p[9]),   k5 = cvtpk_bf16(p[10], p[11]);
    unsigned k6 = cvtpk_bf16(p[12], p[13]), k7 = cvtpk_bf16(p[14], p[15]);
    swap32(k0, k2); swap32(k1, k3); swap32(k4, k6); swap32(k5, k7);
    uint4v u1 = {k0, k1, k2, k3};
    uint4v u2 = {k4, k5, k6, k7};
    short8 pa1 = __builtin_bit_cast(short8, u1);
    short8 pa2 = __builtin_bit_cast(short8, u2);

    const int vrow = l31 * 360 + jt * 32;
    short8 vb1 = *(const short8*)&Vt[vrow + ((half * 8) ^ swz)];
    short8 vb2 = *(const short8*)&Vt[vrow + ((half * 8 + 16) ^ swz)];
    O = MFMA(pa1, vb1, O, 0, 0, 0);
    O = MFMA(pa2, vb2, O, 0, 0, 0);
  }

  float inv = 1.0f / l_run;
#pragma unroll
  for (int r = 0; r < 16; ++r) {
    int iD = (r & 3) + ((r >> 2) << 3) + (half << 2);
    float invr = __shfl(inv, iD, 64);
    int i = i0 + iD;
    if (i < N) outw[(size_t)i * DIM + l31] = O[r] * invr;
  }
}

// ---------------------------------------------------------------------------
// Kernel 2: fused QKV projection + attention. One block per (window, head),
// 768 threads = 12 waves, one M-tile per wave (wave 11 = staging helper).
// Phase-1 async-STAGE split (T14). NEW vs R14: X staged as SINGLE bf16
// (X-lo term dropped; W keeps hi/lo) -> 6 MFMA/kc/wave instead of 9,
// X staging VALU+LDS traffic halved. Precision: x rounded to bf16 adds
// ~0.002 relative error to q/k/v — within the 3x absmax headroom.
// ---------------------------------------------------------------------------
__global__ __launch_bounds__(768, 3) void attn_kernel(
    const float* __restrict__ x, const float* __restrict__ wqkv,
    const float* __restrict__ prep, float* __restrict__ out) {
  const int b = blockIdx.x;
  const int sw = (b & 7) * ((int)gridDim.x >> 3) + (b >> 3);  // XCD swizzle
  const int h = sw & 3;
  const int w = sw >> 2;
  const int tid = threadIdx.x;
  const int lane = tid & 63;
  const int wv = tid >> 6;        // 0..11
  const int l31 = lane & 31;
  const int half = lane >> 5;

  __shared__ __align__(16) unsigned short lds[25600];   // 51200 B
  unsigned short* Xh = lds;             // [352][24]  (phase 1)
  unsigned short* Wh = lds + 8448;      // [96][24]
  unsigned short* Wl = lds + 10752;     // [96][24]
  unsigned short* Kb = lds;             // [352][40]  (phase 2, aliased)
  unsigned short* Vt = lds + 14080;     // [32][360]

  const float* xw = x + (size_t)w * (N * DIM);
  const int xsw = ((l31 >> 3) & 1) << 3;   // 1-bit swizzle for X/W frag reads
  const bool act = (wv < 11);

  // ---- staging geometry (fixed per thread) ----
  const int xrow0 = tid >> 2,  xg0 = (tid & 3) << 2;           // job 0 (all)
  const int idx1  = tid + 768;
  const int xrow1 = idx1 >> 2, xg1 = (idx1 & 3) << 2;          // job 1
  const bool hasx1 = (idx1 < 1408);
  const bool hasw  = (tid < 384);
  const int wc = tid % 96, wkg = (tid / 96) << 2;
  const int wcol = ((wc >> 5) << 7) + h * DH + (wc & 31);
  const int xgs0 = xg0 ^ (((xrow0 >> 3) & 1) << 3);
  const int xgs1 = xg1 ^ (((xrow1 >> 3) & 1) << 3);
  const int wkgs = wkg ^ (((wc >> 3) & 1) << 3);

  float4v xr0v = {0.f, 0.f, 0.f, 0.f}, xr1v = {0.f, 0.f, 0.f, 0.f};
  float wr0 = 0.f, wr1 = 0.f, wr2 = 0.f, wr3 = 0.f;

#define LOAD_STAGE(kc_)                                                     \
  {                                                                         \
    xr0v = *(const float4v*)(xw + xrow0 * DIM + (kc_) * 16 + xg0);          \
    xr1v[0] = 0.f; xr1v[1] = 0.f; xr1v[2] = 0.f; xr1v[3] = 0.f;             \
    if (hasx1 && xrow1 < N)                                                 \
      xr1v = *(const float4v*)(xw + xrow1 * DIM + (kc_) * 16 + xg1);        \
    if (hasw) {                                                             \
      const float* wp_ = wqkv + (size_t)((kc_) * 16 + wkg) * 384 + wcol;    \
      wr0 = wp_[0]; wr1 = wp_[384]; wr2 = wp_[768]; wr3 = wp_[1152];        \
    }                                                                       \
  }

#define WRITE_STAGE()                                                       \
  {                                                                         \
    unsigned h0_, l0_, h1_, l1_;                                            \
    h0_ = cvtpk_bf16(xr0v[0], xr0v[1]);                                     \
    h1_ = cvtpk_bf16(xr0v[2], xr0v[3]);                                     \
    uint2v hv_ = {h0_, h1_};                                                \
    *(uint2v*)&Xh[xrow0 * 24 + xgs0] = hv_;                                 \
    if (hasx1) {                                                            \
      h0_ = cvtpk_bf16(xr1v[0], xr1v[1]);                                   \
      h1_ = cvtpk_bf16(xr1v[2], xr1v[3]);                                   \
      uint2v hv2_ = {h0_, h1_};                                             \
      *(uint2v*)&Xh[xrow1 * 24 + xgs1] = hv2_;                              \
    }                                                                       \
    if (hasw) {                                                             \
      split2pk(wr0, wr1, h0_, l0_);                                         \
      split2pk(wr2, wr3, h1_, l1_);                                         \
      uint2v hw_ = {h0_, h1_}, lw_ = {l0_, l1_};                            \
      *(uint2v*)&Wh[wc * 24 + wkgs] = hw_;                                  \
      *(uint2v*)&Wl[wc * 24 + wkgs] = lw_;                                  \
    }                                                                       \
  }

  f32x16 aQ, aK, aV;
#pragma unroll
  for (int r = 0; r < 16; ++r) { aQ[r] = 0.f; aK[r] = 0.f; aV[r] = 0.f; }

  // ---------------- Phase 1: QKV projection, k-chunks of 16 ----------------
  LOAD_STAGE(0);
  for (int kc = 0; kc < 8; ++kc) {
    __syncthreads();            // previous chunk's LDS reads complete
    WRITE_STAGE();              // cvt + LDS write of this chunk
    __syncthreads();            // staging visible
    if (kc < 7) LOAD_STAGE(kc + 1);   // issue next chunk's loads NOW

    if (act) {
      const int fo = (half * 8) ^ xsw;
      const int xb = (wv * 32 + l31) * 24 + fo;
      short8 xh = *(const short8*)&Xh[xb];
      {  // Q: TRANSPOSED -> A = Wq(hi,lo), B = X
        int wb = l31 * 24 + fo;
        short8 wh8 = *(const short8*)&Wh[wb];
        short8 wl8 = *(const short8*)&Wl[wb];
        aQ = MFMA(wh8, xh, aQ, 0, 0, 0);
        aQ = MFMA(wl8, xh, aQ, 0, 0, 0);
      }
      {  // K: A = X, B = Wk(hi,lo)
        int wb = (32 + l31) * 24 + fo;
        short8 wh8 = *(const short8*)&Wh[wb];
        short8 wl8 = *(const short8*)&Wl[wb];
        aK = MFMA(xh, wh8, aK, 0, 0, 0);
        aK = MFMA(xh, wl8, aK, 0, 0, 0);
      }
      {  // V: A = X, B = Wv(hi,lo)
        int wb = (64 + l31) * 24 + fo;
        short8 wh8 = *(const short8*)&Wh[wb];
        short8 wl8 = *(const short8*)&Wl[wb];
        aV = MFMA(xh, wh8, aV, 0, 0, 0);
        aV = MFMA(xh, wl8, aV, 0, 0, 0);
      }
    }
  }

  __syncthreads();  // all X/W reads done; safe to overwrite with K/V

  // ---- Q^T acc -> phase-2 B-fragment, fully in registers ----
  const float QS = 0.17677669529663687f * 1.4426950408889634f;  // /sqrt(32)*log2e
  uint4v qA = {0, 0, 0, 0}, qB = {0, 0, 0, 0};
  const int swz = ((l31 >> 3) & 3) << 3;
  if (act) {
    unsigned g0 = cvtpk_bf16(aQ[0] * QS, aQ[1] * QS);
    unsigned g1 = cvtpk_bf16(aQ[2] * QS, aQ[3] * QS);
    unsigned g2 = cvtpk_bf16(aQ[4] * QS, aQ[5] * QS);
    unsigned g3 = cvtpk_bf16(aQ[6] * QS, aQ[7] * QS);
    unsigned g4 = cvtpk_bf16(aQ[8] * QS, aQ[9] * QS);
    unsigned g5 = cvtpk_bf16(aQ[10] * QS, aQ[11] * QS);
    unsigned g6 = cvtpk_bf16(aQ[12] * QS, aQ[13] * QS);
    unsigned g7 = cvtpk_bf16(aQ[14] * QS, aQ[15] * QS);
    swap32(g0, g2); swap32(g1, g3); swap32(g4, g6); swap32(g5, g7);
    qA[0] = g0; qA[1] = g1; qA[2] = g2; qA[3] = g3;
    qB[0] = g4; qB[1] = g5; qB[2] = g6; qB[3] = g7;

    // K -> LDS (2-bit XOR col swizzle)
#pragma unroll
    for (int r = 0; r < 16; ++r) {
      int iD = (r & 3) + ((r >> 2) << 3) + (half << 2);
      int cs = l31 ^ ((r >> 2) << 3);
      Kb[(wv * 32 + iD) * 40 + cs] = bf16u(aK[r]);
    }
    // V -> LDS transposed, stride 360, token-swizzled by (d&24)
#pragma unroll
    for (int r = 0; r < 16; r += 2) {
      int j0 = (r & 3) + ((r >> 2) << 3) + (half << 2);
      *(unsigned*)&Vt[l31 * 360 + wv * 32 + (j0 ^ swz)] =
          cvtpk_bf16(aV[r], aV[r + 1]);
    }
  }
  __syncthreads();

  // ---------------- Phase 2: attention ----------------
  if (act) {
    const float* bp = prep + ((size_t)(h * 22 + half) * NP) * 16;
    float* outw = out + (size_t)w * N * DIM + h * DH;
    attend(wv * 32, qA, qB, Kb, Vt, bp, outw, l31, half, swz);
  }
}

// ---------------------------------------------------------------------------
// Kernel 3: out-projection, in-place on d_out, hi/lo split MFMA.
// One block per window, 768 threads (12 waves). Wave wv<=10 owns M-tile wv,
// all 4 N-tiles (acc[4] = 64 AGPR -> 3 waves/SIMD).
// ---------------------------------------------------------------------------
__global__ __launch_bounds__(768, 3) void proj_kernel(
    const float* __restrict__ wout, float* __restrict__ out) {
  const int w = blockIdx.x;
  const int tid = threadIdx.x;
  const int lane = tid & 63, wv = tid >> 6, l31 = lane & 31, half = lane >> 5;
  __shared__ __align__(16) unsigned short lds[38400];     // 76800 B
  unsigned short* Oh = lds;               // [352][40]
  unsigned short* Ol = lds + 14080;
  unsigned short* W2h = lds + 28160;      // [128][40]
  unsigned short* W2l = lds + 33280;
  float* ow = out + (size_t)w * N * DIM;
  const int swz = ((l31 >> 3) & 3) << 3;
  const bool act = (wv < 11);

  f32x16 acc[4];
#pragma unroll
  for (int s = 0; s < 4; ++s)
#pragma unroll
    for (int r = 0; r < 16; ++r) acc[s][r] = 0.f;

  for (int kc = 0; kc < 4; ++kc) {
    __syncthreads();
    // O staging: 2816 quad-groups
#pragma unroll
    for (int p = 0; p < 4; ++p) {
      int idx = tid + p * 768;
      if (idx < 2816) {
        int row = idx >> 3, g = (idx & 7) << 2;
        float4v v = {0.f, 0.f, 0.f, 0.f};
        if (row < N) v = *(const float4v*)(ow + row * DIM + kc * 32 + g);
        unsigned h0, l0, h1, l1;
        split2pk(v[0], v[1], h0, l0);
        split2pk(v[2], v[3], h1, l1);
        uint2v hv = {h0, h1}, lv = {l0, l1};
        int gs = g ^ (((row >> 3) & 3) << 3);
        *(uint2v*)&Oh[row * 40 + gs] = hv;
        *(uint2v*)&Ol[row * 40 + gs] = lv;
      }
    }
    // W2 staging: 1024 quad-jobs (float4 along n, transposed scalar writes)
#pragma unroll
    for (int p = 0; p < 2; ++p) {
      int idx = tid + p * 768;
      if (idx < 1024) {
        int k = idx >> 5, n4 = (idx & 31) << 2;
        float4v v = *(const float4v*)(wout + (size_t)(kc * 32 + k) * DIM + n4);
#pragma unroll
        for (int u = 0; u < 4; ++u) {
          int n = n4 + u;
          int ks = k ^ (((n >> 3) & 3) << 3);
          unsigned short hv = bf16u(v[u]);
          W2h[n * 40 + ks] = hv;
          W2l[n * 40 + ks] =
              bf16u(v[u] - __builtin_bit_cast(float, (unsigned)hv << 16));
        }
      }
    }
    __syncthreads();
    if (act) {
#pragma unroll
      for (int kk = 0; kk < 2; ++kk) {
        int ro = (kk * 16 + half * 8) ^ swz;
        int rb = (wv * 32 + l31) * 40 + ro;
        short8 ah = *(const short8*)&Oh[rb];
        short8 al = *(const short8*)&Ol[rb];
#pragma unroll
        for (int s = 0; s < 4; ++s) {
          int wb = (s * 32 + l31) * 40 + ro;
          short8 bh = *(const short8*)&W2h[wb];
          short8 bl = *(const short8*)&W2l[wb];
          acc[s] = MFMA(ah, bh, acc[s], 0, 0, 0);
          acc[s] = MFMA(ah, bl, acc[s], 0, 0, 0);
          acc[s] = MFMA(al, bh, acc[s], 0, 0, 0);
        }
      }
    }
  }
  if (act) {
#pragma unroll
    for (int s = 0; s < 4; ++s) {
#pragma unroll
      for (int r = 0; r < 16; ++r) {
        int iD = (r & 3) + ((r >> 2) << 3) + (half << 2);
        int i = wv * 32 + iD;
        if (i < N) ow[(size_t)i * DIM + s * 32 + l31] = acc[s][r];
      }
    }
  }
}

// ---------------------------------------------------------------------------
extern "C" void kernel_launch(void* const* d_in, const int* in_sizes, int n_in,
                              void* d_out, int out_size, void* d_ws, size_t ws_size,
                              hipStream_t stream) {
  const float* x     = (const float*)d_in[0];
  const float* wqkv  = (const float*)d_in[1];
  const float* wout  = (const float*)d_in[2];
  const float* table = (const float*)d_in[3];
  const int*   rel   = (const int*)d_in[4];
  float* out  = (float*)d_out;
  float* prep = (float*)d_ws;  // 4*11*2*352*16*4 B = 1.98 MB

  const int B = in_sizes[0] / (N * DIM);  // 512 windows
  const int rows = HEADS * 11 * 2 * NP;   // 30976

  bias_kernel<<<(rows + 255) / 256, 256, 0, stream>>>(table, rel, prep);
  attn_kernel<<<HEADS * B, 768, 0, stream>>>(x, wqkv, prep, out);
  proj_kernel<<<B, 768, 0, stream>>>(wout, out);
}

// Round 17
// 184.167 us; speedup vs baseline: 1.1570x; 1.0417x over previous
//
#include <hip/hip_runtime.h>

#define N 343        // 7*7*7 tokens per window
#define NP 352       // padded to 11 tiles of 32
#define DIM 128
#define HEADS 4
#define DH 32

typedef float  f32x16 __attribute__((ext_vector_type(16)));
typedef float  float4v __attribute__((ext_vector_type(4)));
typedef short  short8 __attribute__((ext_vector_type(8)));
typedef unsigned uint4v __attribute__((ext_vector_type(4)));
typedef unsigned uint2v __attribute__((ext_vector_type(2)));

#define MFMA __builtin_amdgcn_mfma_f32_32x32x16_bf16

// ---- gfx950 packed bf16 convert (RNE) and cross-half swap -----------------
static __device__ __forceinline__ unsigned cvtpk_bf16(float lo, float hi) {
  unsigned r;
  asm("v_cvt_pk_bf16_f32 %0, %1, %2" : "=v"(r) : "v"(lo), "v"(hi));
  return r;
}
static __device__ __forceinline__ void swap32(unsigned &a, unsigned &b) {
  asm("v_permlane32_swap_b32 %0, %1" : "+v"(a), "+v"(b));
}
// native base-2 exponential (v_exp_f32 IS exp2 on CDNA)
static __device__ __forceinline__ float exp2v(float x) {
  float r;
  asm("v_exp_f32 %0, %1" : "=v"(r) : "v"(x));
  return r;
}
static __device__ __forceinline__ unsigned short bf16u(float a) {
  unsigned u = __builtin_bit_cast(unsigned, a);
  unsigned r = u + 0x7fffu + ((u >> 16) & 1u);
  return (unsigned short)(r >> 16);
}
static __device__ __forceinline__ void split2pk(float a, float b,
                                                unsigned &hi, unsigned &lo) {
  hi = cvtpk_bf16(a, b);
  float ra = a - __builtin_bit_cast(float, hi << 16);
  float rb = b - __builtin_bit_cast(float, hi & 0xffff0000u);
  lo = cvtpk_bf16(ra, rb);
}

// ---------------------------------------------------------------------------
// Kernel 1: bias gather pre-permuted into the 32x32 MFMA C-fragment order.
// ---------------------------------------------------------------------------
__global__ __launch_bounds__(256) void bias_kernel(
    const float* __restrict__ table, const int* __restrict__ rel,
    float* __restrict__ prep) {
  int row = blockIdx.x * 256 + threadIdx.x;
  if (row >= HEADS * 11 * 2 * NP) return;
  int i = row % NP;
  int t = row / NP;
  int half = t & 1;
  int tj = t >> 1;
  int jt = tj % 11;
  int h = tj / 11;
  float* dst = prep + (size_t)row * 16;
#pragma unroll
  for (int r = 0; r < 16; ++r) {
    int j = jt * 32 + (r & 3) + ((r >> 2) << 3) + (half << 2);
    float v;
    if (j >= N) v = -1.44e30f;
    else if (i >= N) v = 0.f;
    else v = table[rel[i * N + j] * HEADS + h] * 1.4426950408889634f;
    dst[r] = v;
  }
}

// ---------------------------------------------------------------------------
// Phase-2 flash loop, one 32-row M-tile, Q in registers. R11/R14 semantics
// (max-tracked; no-max failed twice — permanent; setprio measured neutral
// and removed). Kb: [352][40] col-swizzled by (row&24). Vt: [32][360]
// token-swizzled (d&24). Bank conflicts NOT on the critical path (measured).
// ---------------------------------------------------------------------------
static __device__ __forceinline__ void attend(
    int i0, uint4v qAu, uint4v qBu,
    const unsigned short* __restrict__ Kb, const unsigned short* __restrict__ Vt,
    const float* __restrict__ bp, float* __restrict__ outw,
    int l31, int half, int swz) {
  short8 q0 = __builtin_bit_cast(short8, qAu);
  short8 q1 = __builtin_bit_cast(short8, qBu);
  const float* bpi = bp + (size_t)(i0 + l31) * 16;

  f32x16 O;
#pragma unroll
  for (int r = 0; r < 16; ++r) O[r] = 0.f;
  float m_run = -3.0e38f, l_run = 0.f;

  f32x16 Tn = *(const f32x16*)(bpi);      // prefetch bias tile 0
  for (int jt = 0; jt < 11; ++jt) {
    f32x16 T = Tn;                        // bias IS the MFMA C-input
    if (jt < 10) Tn = *(const f32x16*)(bpi + (size_t)(jt + 1) * 11264);

    const int krow = (jt * 32 + l31) * 40;
    short8 ka0 = *(const short8*)&Kb[krow + ((half * 8) ^ swz)];
    short8 ka1 = *(const short8*)&Kb[krow + ((half * 8 + 16) ^ swz)];
    T = MFMA(ka0, q0, T, 0, 0, 0);
    T = MFMA(ka1, q1, T, 0, 0, 0);

    float m0 = fmaxf(T[0], T[1]),   m1 = fmaxf(T[2], T[3]);
    float m2 = fmaxf(T[4], T[5]),   m3 = fmaxf(T[6], T[7]);
    float m4 = fmaxf(T[8], T[9]),   m5 = fmaxf(T[10], T[11]);
    float m6 = fmaxf(T[12], T[13]), m7 = fmaxf(T[14], T[15]);
    m0 = fmaxf(m0, m1); m2 = fmaxf(m2, m3);
    m4 = fmaxf(m4, m5); m6 = fmaxf(m6, m7);
    m0 = fmaxf(m0, m2); m4 = fmaxf(m4, m6);
    float pm = fmaxf(m0, m4);
    pm = fmaxf(pm, __shfl_xor(pm, 32, 64));

    if (__any(pm > m_run + 11.5f)) {      // deferred-max rescale (rare)
      float nm = fmaxf(m_run, pm);
      float f = exp2v(m_run - nm);
      l_run *= f;
      m_run = nm;
#pragma unroll
      for (int r = 0; r < 16; ++r) {
        int iD = (r & 3) + ((r >> 2) << 3) + (half << 2);
        O[r] *= __shfl(f, iD, 64);
      }
    }

    float p[16];
#pragma unroll
    for (int r = 0; r < 16; ++r) p[r] = exp2v(T[r] - m_run);
    float s0 = (p[0] + p[1]) + (p[2] + p[3]);
    float s1 = (p[4] + p[5]) + (p[6] + p[7]);
    float s2 = (p[8] + p[9]) + (p[10] + p[11]);
    float s3 = (p[12] + p[13]) + (p[14] + p[15]);
    float ps = (s0 + s1) + (s2 + s3);
    l_run += ps + __shfl_xor(ps, 32, 64);

    unsigned k0 = cvtpk_bf16(p[0], p[1]),   k1 = cvtpk_bf16(p[2], p[3]);
    unsigned k2 = cvtpk_bf16(p[4], p[5]),   k3 = cvtpk_bf16(p[6], p[7]);
    unsigned k4 = cvtpk_bf16(p[8], p[9]),   k5 = cvtpk_bf16(p[10], p[11]);
    unsigned k6 = cvtpk_bf16(p[12], p[13]), k7 = cvtpk_bf16(p[14], p[15]);
    swap32(k0, k2); swap32(k1, k3); swap32(k4, k6); swap32(k5, k7);
    uint4v u1 = {k0, k1, k2, k3};
    uint4v u2 = {k4, k5, k6, k7};
    short8 pa1 = __builtin_bit_cast(short8, u1);
    short8 pa2 = __builtin_bit_cast(short8, u2);

    const int vrow = l31 * 360 + jt * 32;
    short8 vb1 = *(const short8*)&Vt[vrow + ((half * 8) ^ swz)];
    short8 vb2 = *(const short8*)&Vt[vrow + ((half * 8 + 16) ^ swz)];
    O = MFMA(pa1, vb1, O, 0, 0, 0);
    O = MFMA(pa2, vb2, O, 0, 0, 0);
  }

  float inv = 1.0f / l_run;
#pragma unroll
  for (int r = 0; r < 16; ++r) {
    int iD = (r & 3) + ((r >> 2) << 3) + (half << 2);
    float invr = __shfl(inv, iD, 64);
    int i = i0 + iD;
    if (i < N) outw[(size_t)i * DIM + l31] = O[r] * invr;
  }
}

// ---------------------------------------------------------------------------
// Kernel 2: fused QKV projection + attention. One block per (window, head),
// 768 threads = 12 waves, one M-tile per wave (wave 11 = staging helper).
// Phase-1 async-STAGE split (T14). NEW vs R16: W-lo also dropped (full bf16
// phase-1, 3 MFMA/kc/wave). Precision OK because q/k/v are bf16-rounded
// before phase 2 anyway — pre-rounding error from bf16 W (~0.2% rel) is the
// same order as the rounding itself (R16 measured: absmax unchanged when
// X-lo dropped; output error dominated by phase-2 bf16 quantization).
// ---------------------------------------------------------------------------
__global__ __launch_bounds__(768, 3) void attn_kernel(
    const float* __restrict__ x, const float* __restrict__ wqkv,
    const float* __restrict__ prep, float* __restrict__ out) {
  const int b = blockIdx.x;
  const int sw = (b & 7) * ((int)gridDim.x >> 3) + (b >> 3);  // XCD swizzle
  const int h = sw & 3;
  const int w = sw >> 2;
  const int tid = threadIdx.x;
  const int lane = tid & 63;
  const int wv = tid >> 6;        // 0..11
  const int l31 = lane & 31;
  const int half = lane >> 5;

  __shared__ __align__(16) unsigned short lds[25600];   // 51200 B
  unsigned short* Xh = lds;             // [352][24]  (phase 1)
  unsigned short* Wh = lds + 8448;      // [96][24]
  unsigned short* Kb = lds;             // [352][40]  (phase 2, aliased)
  unsigned short* Vt = lds + 14080;     // [32][360]

  const float* xw = x + (size_t)w * (N * DIM);
  const int xsw = ((l31 >> 3) & 1) << 3;   // 1-bit swizzle for X/W frag reads
  const bool act = (wv < 11);

  // ---- staging geometry (fixed per thread) ----
  const int xrow0 = tid >> 2,  xg0 = (tid & 3) << 2;           // job 0 (all)
  const int idx1  = tid + 768;
  const int xrow1 = idx1 >> 2, xg1 = (idx1 & 3) << 2;          // job 1
  const bool hasx1 = (idx1 < 1408);
  const bool hasw  = (tid < 384);
  const int wc = tid % 96, wkg = (tid / 96) << 2;
  const int wcol = ((wc >> 5) << 7) + h * DH + (wc & 31);
  const int xgs0 = xg0 ^ (((xrow0 >> 3) & 1) << 3);
  const int xgs1 = xg1 ^ (((xrow1 >> 3) & 1) << 3);
  const int wkgs = wkg ^ (((wc >> 3) & 1) << 3);

  float4v xr0v = {0.f, 0.f, 0.f, 0.f}, xr1v = {0.f, 0.f, 0.f, 0.f};
  float wr0 = 0.f, wr1 = 0.f, wr2 = 0.f, wr3 = 0.f;

#define LOAD_STAGE(kc_)                                                     \
  {                                                                         \
    xr0v = *(const float4v*)(xw + xrow0 * DIM + (kc_) * 16 + xg0);          \
    xr1v[0] = 0.f; xr1v[1] = 0.f; xr1v[2] = 0.f; xr1v[3] = 0.f;             \
    if (hasx1 && xrow1 < N)                                                 \
      xr1v = *(const float4v*)(xw + xrow1 * DIM + (kc_) * 16 + xg1);        \
    if (hasw) {                                                             \
      const float* wp_ = wqkv + (size_t)((kc_) * 16 + wkg) * 384 + wcol;    \
      wr0 = wp_[0]; wr1 = wp_[384]; wr2 = wp_[768]; wr3 = wp_[1152];        \
    }                                                                       \
  }

#define WRITE_STAGE()                                                       \
  {                                                                         \
    unsigned h0_, h1_;                                                      \
    h0_ = cvtpk_bf16(xr0v[0], xr0v[1]);                                     \
    h1_ = cvtpk_bf16(xr0v[2], xr0v[3]);                                     \
    uint2v hv_ = {h0_, h1_};                                                \
    *(uint2v*)&Xh[xrow0 * 24 + xgs0] = hv_;                                 \
    if (hasx1) {                                                            \
      h0_ = cvtpk_bf16(xr1v[0], xr1v[1]);                                   \
      h1_ = cvtpk_bf16(xr1v[2], xr1v[3]);                                   \
      uint2v hv2_ = {h0_, h1_};                                             \
      *(uint2v*)&Xh[xrow1 * 24 + xgs1] = hv2_;                              \
    }                                                                       \
    if (hasw) {                                                             \
      h0_ = cvtpk_bf16(wr0, wr1);                                           \
      h1_ = cvtpk_bf16(wr2, wr3);                                           \
      uint2v hw_ = {h0_, h1_};                                              \
      *(uint2v*)&Wh[wc * 24 + wkgs] = hw_;                                  \
    }                                                                       \
  }

  f32x16 aQ, aK, aV;
#pragma unroll
  for (int r = 0; r < 16; ++r) { aQ[r] = 0.f; aK[r] = 0.f; aV[r] = 0.f; }

  // ---------------- Phase 1: QKV projection, k-chunks of 16 ----------------
  LOAD_STAGE(0);
  for (int kc = 0; kc < 8; ++kc) {
    __syncthreads();            // previous chunk's LDS reads complete
    WRITE_STAGE();              // cvt + LDS write of this chunk
    __syncthreads();            // staging visible
    if (kc < 7) LOAD_STAGE(kc + 1);   // issue next chunk's loads NOW

    if (act) {
      const int fo = (half * 8) ^ xsw;
      const int xb = (wv * 32 + l31) * 24 + fo;
      short8 xh = *(const short8*)&Xh[xb];
      {  // Q: TRANSPOSED -> A = Wq, B = X
        short8 wh8 = *(const short8*)&Wh[l31 * 24 + fo];
        aQ = MFMA(wh8, xh, aQ, 0, 0, 0);
      }
      {  // K: A = X, B = Wk
        short8 wh8 = *(const short8*)&Wh[(32 + l31) * 24 + fo];
        aK = MFMA(xh, wh8, aK, 0, 0, 0);
      }
      {  // V: A = X, B = Wv
        short8 wh8 = *(const short8*)&Wh[(64 + l31) * 24 + fo];
        aV = MFMA(xh, wh8, aV, 0, 0, 0);
      }
    }
  }

  __syncthreads();  // all X/W reads done; safe to overwrite with K/V

  // ---- Q^T acc -> phase-2 B-fragment, fully in registers ----
  const float QS = 0.17677669529663687f * 1.4426950408889634f;  // /sqrt(32)*log2e
  uint4v qA = {0, 0, 0, 0}, qB = {0, 0, 0, 0};
  const int swz = ((l31 >> 3) & 3) << 3;
  if (act) {
    unsigned g0 = cvtpk_bf16(aQ[0] * QS, aQ[1] * QS);
    unsigned g1 = cvtpk_bf16(aQ[2] * QS, aQ[3] * QS);
    unsigned g2 = cvtpk_bf16(aQ[4] * QS, aQ[5] * QS);
    unsigned g3 = cvtpk_bf16(aQ[6] * QS, aQ[7] * QS);
    unsigned g4 = cvtpk_bf16(aQ[8] * QS, aQ[9] * QS);
    unsigned g5 = cvtpk_bf16(aQ[10] * QS, aQ[11] * QS);
    unsigned g6 = cvtpk_bf16(aQ[12] * QS, aQ[13] * QS);
    unsigned g7 = cvtpk_bf16(aQ[14] * QS, aQ[15] * QS);
    swap32(g0, g2); swap32(g1, g3); swap32(g4, g6); swap32(g5, g7);
    qA[0] = g0; qA[1] = g1; qA[2] = g2; qA[3] = g3;
    qB[0] = g4; qB[1] = g5; qB[2] = g6; qB[3] = g7;

    // K -> LDS (2-bit XOR col swizzle)
#pragma unroll
    for (int r = 0; r < 16; ++r) {
      int iD = (r & 3) + ((r >> 2) << 3) + (half << 2);
      int cs = l31 ^ ((r >> 2) << 3);
      Kb[(wv * 32 + iD) * 40 + cs] = bf16u(aK[r]);
    }
    // V -> LDS transposed, stride 360, token-swizzled by (d&24)
#pragma unroll
    for (int r = 0; r < 16; r += 2) {
      int j0 = (r & 3) + ((r >> 2) << 3) + (half << 2);
      *(unsigned*)&Vt[l31 * 360 + wv * 32 + (j0 ^ swz)] =
          cvtpk_bf16(aV[r], aV[r + 1]);
    }
  }
  __syncthreads();

  // ---------------- Phase 2: attention ----------------
  if (act) {
    const float* bp = prep + ((size_t)(h * 22 + half) * NP) * 16;
    float* outw = out + (size_t)w * N * DIM + h * DH;
    attend(wv * 32, qA, qB, Kb, Vt, bp, outw, l31, half, swz);
  }
}

// ---------------------------------------------------------------------------
// Kernel 3: out-projection, in-place on d_out. NEW vs R16: O-lo dropped
// (mirror of attn's X-lo drop; W2 keeps hi/lo) -> 2 MFMA per tile-step
// instead of 3; O staging VALU+LDS halved.
// One block per window, 768 threads (12 waves). Wave wv<=10 owns M-tile wv.
// ---------------------------------------------------------------------------
__global__ __launch_bounds__(768, 3) void proj_kernel(
    const float* __restrict__ wout, float* __restrict__ out) {
  const int w = blockIdx.x;
  const int tid = threadIdx.x;
  const int lane = tid & 63, wv = tid >> 6, l31 = lane & 31, half = lane >> 5;
  __shared__ __align__(16) unsigned short lds[24320];     // 48640 B
  unsigned short* Oh = lds;               // [352][40]
  unsigned short* W2h = lds + 14080;      // [128][40]
  unsigned short* W2l = lds + 19200;      // [128][40]
  float* ow = out + (size_t)w * N * DIM;
  const int swz = ((l31 >> 3) & 3) << 3;
  const bool act = (wv < 11);

  f32x16 acc[4];
#pragma unroll
  for (int s = 0; s < 4; ++s)
#pragma unroll
    for (int r = 0; r < 16; ++r) acc[s][r] = 0.f;

  for (int kc = 0; kc < 4; ++kc) {
    __syncthreads();
    // O staging: 2816 quad-groups (hi only)
#pragma unroll
    for (int p = 0; p < 4; ++p) {
      int idx = tid + p * 768;
      if (idx < 2816) {
        int row = idx >> 3, g = (idx & 7) << 2;
        float4v v = {0.f, 0.f, 0.f, 0.f};
        if (row < N) v = *(const float4v*)(ow + row * DIM + kc * 32 + g);
        unsigned h0 = cvtpk_bf16(v[0], v[1]);
        unsigned h1 = cvtpk_bf16(v[2], v[3]);
        uint2v hv = {h0, h1};
        int gs = g ^ (((row >> 3) & 3) << 3);
        *(uint2v*)&Oh[row * 40 + gs] = hv;
      }
    }
    // W2 staging: 1024 quad-jobs (float4 along n, transposed scalar writes)
#pragma unroll
    for (int p = 0; p < 2; ++p) {
      int idx = tid + p * 768;
      if (idx < 1024) {
        int k = idx >> 5, n4 = (idx & 31) << 2;
        float4v v = *(const float4v*)(wout + (size_t)(kc * 32 + k) * DIM + n4);
#pragma unroll
        for (int u = 0; u < 4; ++u) {
          int n = n4 + u;
          int ks = k ^ (((n >> 3) & 3) << 3);
          unsigned short hv = bf16u(v[u]);
          W2h[n * 40 + ks] = hv;
          W2l[n * 40 + ks] =
              bf16u(v[u] - __builtin_bit_cast(float, (unsigned)hv << 16));
        }
      }
    }
    __syncthreads();
    if (act) {
#pragma unroll
      for (int kk = 0; kk < 2; ++kk) {
        int ro = (kk * 16 + half * 8) ^ swz;
        int rb = (wv * 32 + l31) * 40 + ro;
        short8 ah = *(const short8*)&Oh[rb];
#pragma unroll
        for (int s = 0; s < 4; ++s) {
          int wb = (s * 32 + l31) * 40 + ro;
          short8 bh = *(const short8*)&W2h[wb];
          short8 bl = *(const short8*)&W2l[wb];
          acc[s] = MFMA(ah, bh, acc[s], 0, 0, 0);
          acc[s] = MFMA(ah, bl, acc[s], 0, 0, 0);
        }
      }
    }
  }
  if (act) {
#pragma unroll
    for (int s = 0; s < 4; ++s) {
#pragma unroll
      for (int r = 0; r < 16; ++r) {
        int iD = (r & 3) + ((r >> 2) << 3) + (half << 2);
        int i = wv * 32 + iD;
        if (i < N) ow[(size_t)i * DIM + s * 32 + l31] = acc[s][r];
      }
    }
  }
}

// ---------------------------------------------------------------------------
extern "C" void kernel_launch(void* const* d_in, const int* in_sizes, int n_in,
                              void* d_out, int out_size, void* d_ws, size_t ws_size,
                              hipStream_t stream) {
  const float* x     = (const float*)d_in[0];
  const float* wqkv  = (const float*)d_in[1];
  const float* wout  = (const float*)d_in[2];
  const float* table = (const float*)d_in[3];
  const int*   rel   = (const int*)d_in[4];
  float* out  = (float*)d_out;
  float* prep = (float*)d_ws;  // 4*11*2*352*16*4 B = 1.98 MB

  const int B = in_sizes[0] / (N * DIM);  // 512 windows
  const int rows = HEADS * 11 * 2 * NP;   // 30976

  bias_kernel<<<(rows + 255) / 256, 256, 0, stream>>>(table, rel, prep);
  attn_kernel<<<HEADS * B, 768, 0, stream>>>(x, wqkv, prep, out);
  proj_kernel<<<B, 768, 0, stream>>>(wout, out);
}

// Round 18
// 173.640 us; speedup vs baseline: 1.2271x; 1.0606x over previous
//
#include <hip/hip_runtime.h>

#define N 343        // 7*7*7 tokens per window
#define NP 352       // padded to 11 tiles of 32
#define DIM 128
#define HEADS 4
#define DH 32

typedef float  f32x16 __attribute__((ext_vector_type(16)));
typedef float  float4v __attribute__((ext_vector_type(4)));
typedef short  short8 __attribute__((ext_vector_type(8)));
typedef unsigned uint4v __attribute__((ext_vector_type(4)));
typedef unsigned uint2v __attribute__((ext_vector_type(2)));

#define MFMA __builtin_amdgcn_mfma_f32_32x32x16_bf16

// ---- gfx950 packed bf16 convert (RNE) and cross-half swap -----------------
static __device__ __forceinline__ unsigned cvtpk_bf16(float lo, float hi) {
  unsigned r;
  asm("v_cvt_pk_bf16_f32 %0, %1, %2" : "=v"(r) : "v"(lo), "v"(hi));
  return r;
}
static __device__ __forceinline__ void swap32(unsigned &a, unsigned &b) {
  asm("v_permlane32_swap_b32 %0, %1" : "+v"(a), "+v"(b));
}
// native base-2 exponential (v_exp_f32 IS exp2 on CDNA)
static __device__ __forceinline__ float exp2v(float x) {
  float r;
  asm("v_exp_f32 %0, %1" : "=v"(r) : "v"(x));
  return r;
}
static __device__ __forceinline__ unsigned short bf16u(float a) {
  unsigned u = __builtin_bit_cast(unsigned, a);
  unsigned r = u + 0x7fffu + ((u >> 16) & 1u);
  return (unsigned short)(r >> 16);
}
static __device__ __forceinline__ void split2pk(float a, float b,
                                                unsigned &hi, unsigned &lo) {
  hi = cvtpk_bf16(a, b);
  float ra = a - __builtin_bit_cast(float, hi << 16);
  float rb = b - __builtin_bit_cast(float, hi & 0xffff0000u);
  lo = cvtpk_bf16(ra, rb);
}

// ---------------------------------------------------------------------------
// Kernel 1: bias gather pre-permuted into the 32x32 MFMA C-fragment order.
// ---------------------------------------------------------------------------
__global__ __launch_bounds__(256) void bias_kernel(
    const float* __restrict__ table, const int* __restrict__ rel,
    float* __restrict__ prep) {
  int row = blockIdx.x * 256 + threadIdx.x;
  if (row >= HEADS * 11 * 2 * NP) return;
  int i = row % NP;
  int t = row / NP;
  int half = t & 1;
  int tj = t >> 1;
  int jt = tj % 11;
  int h = tj / 11;
  float* dst = prep + (size_t)row * 16;
#pragma unroll
  for (int r = 0; r < 16; ++r) {
    int j = jt * 32 + (r & 3) + ((r >> 2) << 3) + (half << 2);
    float v;
    if (j >= N) v = -1.44e30f;
    else if (i >= N) v = 0.f;
    else v = table[rel[i * N + j] * HEADS + h] * 1.4426950408889634f;
    dst[r] = v;
  }
}

// ---------------------------------------------------------------------------
// Phase-2 flash loop, one 32-row M-tile, Q in registers. R11/R14 semantics
// (max-tracked; no-max failed twice — permanent; setprio measured neutral
// and removed). Kb: [352][40] col-swizzled by (row&24). Vt: [32][360]
// token-swizzled (d&24). Bank conflicts NOT on the critical path (measured).
// ---------------------------------------------------------------------------
static __device__ __forceinline__ void attend(
    int i0, uint4v qAu, uint4v qBu,
    const unsigned short* __restrict__ Kb, const unsigned short* __restrict__ Vt,
    const float* __restrict__ bp, float* __restrict__ outw,
    int l31, int half, int swz) {
  short8 q0 = __builtin_bit_cast(short8, qAu);
  short8 q1 = __builtin_bit_cast(short8, qBu);
  const float* bpi = bp + (size_t)(i0 + l31) * 16;

  f32x16 O;
#pragma unroll
  for (int r = 0; r < 16; ++r) O[r] = 0.f;
  float m_run = -3.0e38f, l_run = 0.f;

  f32x16 Tn = *(const f32x16*)(bpi);      // prefetch bias tile 0
  for (int jt = 0; jt < 11; ++jt) {
    f32x16 T = Tn;                        // bias IS the MFMA C-input
    if (jt < 10) Tn = *(const f32x16*)(bpi + (size_t)(jt + 1) * 11264);

    const int krow = (jt * 32 + l31) * 40;
    short8 ka0 = *(const short8*)&Kb[krow + ((half * 8) ^ swz)];
    short8 ka1 = *(const short8*)&Kb[krow + ((half * 8 + 16) ^ swz)];
    T = MFMA(ka0, q0, T, 0, 0, 0);
    T = MFMA(ka1, q1, T, 0, 0, 0);

    float m0 = fmaxf(T[0], T[1]),   m1 = fmaxf(T[2], T[3]);
    float m2 = fmaxf(T[4], T[5]),   m3 = fmaxf(T[6], T[7]);
    float m4 = fmaxf(T[8], T[9]),   m5 = fmaxf(T[10], T[11]);
    float m6 = fmaxf(T[12], T[13]), m7 = fmaxf(T[14], T[15]);
    m0 = fmaxf(m0, m1); m2 = fmaxf(m2, m3);
    m4 = fmaxf(m4, m5); m6 = fmaxf(m6, m7);
    m0 = fmaxf(m0, m2); m4 = fmaxf(m4, m6);
    float pm = fmaxf(m0, m4);
    pm = fmaxf(pm, __shfl_xor(pm, 32, 64));

    if (__any(pm > m_run + 11.5f)) {      // deferred-max rescale (rare)
      float nm = fmaxf(m_run, pm);
      float f = exp2v(m_run - nm);
      l_run *= f;
      m_run = nm;
#pragma unroll
      for (int r = 0; r < 16; ++r) {
        int iD = (r & 3) + ((r >> 2) << 3) + (half << 2);
        O[r] *= __shfl(f, iD, 64);
      }
    }

    float p[16];
#pragma unroll
    for (int r = 0; r < 16; ++r) p[r] = exp2v(T[r] - m_run);
    float s0 = (p[0] + p[1]) + (p[2] + p[3]);
    float s1 = (p[4] + p[5]) + (p[6] + p[7]);
    float s2 = (p[8] + p[9]) + (p[10] + p[11]);
    float s3 = (p[12] + p[13]) + (p[14] + p[15]);
    float ps = (s0 + s1) + (s2 + s3);
    l_run += ps + __shfl_xor(ps, 32, 64);

    unsigned k0 = cvtpk_bf16(p[0], p[1]),   k1 = cvtpk_bf16(p[2], p[3]);
    unsigned k2 = cvtpk_bf16(p[4], p[5]),   k3 = cvtpk_bf16(p[6], p[7]);
    unsigned k4 = cvtpk_bf16(p[8], p[9]),   k5 = cvtpk_bf16(p[10], p[11]);
    unsigned k6 = cvtpk_bf16(p[12], p[13]), k7 = cvtpk_bf16(p[14], p[15]);
    swap32(k0, k2); swap32(k1, k3); swap32(k4, k6); swap32(k5, k7);
    uint4v u1 = {k0, k1, k2, k3};
    uint4v u2 = {k4, k5, k6, k7};
    short8 pa1 = __builtin_bit_cast(short8, u1);
    short8 pa2 = __builtin_bit_cast(short8, u2);

    const int vrow = l31 * 360 + jt * 32;
    short8 vb1 = *(const short8*)&Vt[vrow + ((half * 8) ^ swz)];
    short8 vb2 = *(const short8*)&Vt[vrow + ((half * 8 + 16) ^ swz)];
    O = MFMA(pa1, vb1, O, 0, 0, 0);
    O = MFMA(pa2, vb2, O, 0, 0, 0);
  }

  float inv = 1.0f / l_run;
#pragma unroll
  for (int r = 0; r < 16; ++r) {
    int iD = (r & 3) + ((r >> 2) << 3) + (half << 2);
    float invr = __shfl(inv, iD, 64);
    int i = i0 + iD;
    if (i < N) outw[(size_t)i * DIM + l31] = O[r] * invr;
  }
}

// ---------------------------------------------------------------------------
// Kernel 2: fused QKV projection + attention. One block per (window, head),
// 768 threads = 12 waves, one M-tile per wave (wave 11 = staging helper).
// NEW vs R17: W (head slice, 96x128 bf16 = 24KB) staged ONCE into resident
// LDS Wf[96][136] (stride 136 u16 = 68 dw == 4 mod 32 -> conflict-free
// fragment reads, no swizzle); X double-buffered -> ONE barrier per kc
// (was 2) and zero per-kc W staging. T14 load-issue placement preserved.
// Safety: MFMA(kc-2) reads of buf A precede barrier(kc-1) which precedes
// WRITE(kc) into A — single-barrier induction.
// ---------------------------------------------------------------------------
__global__ __launch_bounds__(768, 3) void attn_kernel(
    const float* __restrict__ x, const float* __restrict__ wqkv,
    const float* __restrict__ prep, float* __restrict__ out) {
  const int b = blockIdx.x;
  const int sw = (b & 7) * ((int)gridDim.x >> 3) + (b >> 3);  // XCD swizzle
  const int h = sw & 3;
  const int w = sw >> 2;
  const int tid = threadIdx.x;
  const int lane = tid & 63;
  const int wv = tid >> 6;        // 0..11
  const int l31 = lane & 31;
  const int half = lane >> 5;

  __shared__ __align__(16) unsigned short lds[29952];   // 59904 B
  unsigned short* Xb0 = lds;            // [352][24]  (phase 1, buf 0)
  unsigned short* Xb1 = lds + 8448;     // [352][24]  (phase 1, buf 1)
  unsigned short* Wf  = lds + 16896;    // [96][136]  (phase 1, resident W)
  unsigned short* Kb = lds;             // [352][40]  (phase 2, aliased)
  unsigned short* Vt = lds + 14080;     // [32][360]

  const float* xw = x + (size_t)w * (N * DIM);
  const int xsw = ((l31 >> 3) & 1) << 3;   // 1-bit swizzle for X frag reads
  const bool act = (wv < 11);

  // ---- staging geometry (fixed per thread) ----
  const int xrow0 = tid >> 2,  xg0 = (tid & 3) << 2;           // job 0 (all)
  const int idx1  = tid + 768;
  const int xrow1 = idx1 >> 2, xg1 = (idx1 & 3) << 2;          // job 1
  const bool hasx1 = (idx1 < 1408);
  const int xgs0 = xg0 ^ (((xrow0 >> 3) & 1) << 3);
  const int xgs1 = xg1 ^ (((xrow1 >> 3) & 1) << 3);

  float4v xr0v = {0.f, 0.f, 0.f, 0.f}, xr1v = {0.f, 0.f, 0.f, 0.f};

#define LOAD_STAGE(kc_)                                                     \
  {                                                                         \
    xr0v = *(const float4v*)(xw + xrow0 * DIM + (kc_) * 16 + xg0);          \
    xr1v[0] = 0.f; xr1v[1] = 0.f; xr1v[2] = 0.f; xr1v[3] = 0.f;             \
    if (hasx1 && xrow1 < N)                                                 \
      xr1v = *(const float4v*)(xw + xrow1 * DIM + (kc_) * 16 + xg1);        \
  }

#define WRITE_STAGE(XB_)                                                    \
  {                                                                         \
    unsigned h0_, h1_;                                                      \
    h0_ = cvtpk_bf16(xr0v[0], xr0v[1]);                                     \
    h1_ = cvtpk_bf16(xr0v[2], xr0v[3]);                                     \
    uint2v hv_ = {h0_, h1_};                                                \
    *(uint2v*)&(XB_)[xrow0 * 24 + xgs0] = hv_;                              \
    if (hasx1) {                                                            \
      h0_ = cvtpk_bf16(xr1v[0], xr1v[1]);                                   \
      h1_ = cvtpk_bf16(xr1v[2], xr1v[3]);                                   \
      uint2v hv2_ = {h0_, h1_};                                             \
      *(uint2v*)&(XB_)[xrow1 * 24 + xgs1] = hv2_;                           \
    }                                                                       \
  }

  f32x16 aQ, aK, aV;
#pragma unroll
  for (int r = 0; r < 16; ++r) { aQ[r] = 0.f; aK[r] = 0.f; aV[r] = 0.f; }

  // ---------------- Phase 1 prologue: X chunk 0 + resident W ----------------
  LOAD_STAGE(0);
  // one-time W stage: 3072 jobs (c 0..95, k-groups of 4)
#pragma unroll
  for (int p = 0; p < 4; ++p) {
    int idx = tid + p * 768;
    int c = idx % 96, kg = (idx / 96) << 2;
    int col = ((c >> 5) << 7) + h * DH + (c & 31);
    const float* wp = wqkv + (size_t)kg * 384 + col;
#pragma unroll
    for (int u = 0; u < 4; ++u)
      Wf[c * 136 + kg + u] = bf16u(wp[(size_t)u * 384]);
  }

  // ---------------- Phase 1 main: one barrier per kc ----------------
  for (int kc = 0; kc < 8; ++kc) {
    unsigned short* cur = (kc & 1) ? Xb1 : Xb0;
    WRITE_STAGE(cur);                 // regs from LOAD of last iter
    if (kc < 7) LOAD_STAGE(kc + 1);   // issue next chunk's loads NOW
    __syncthreads();                  // cur visible; (kc-2) reads retired

    if (act) {
      const int fo = (half * 8) ^ xsw;
      const int wfo = kc * 16 + half * 8;
      short8 xh = *(const short8*)&cur[(wv * 32 + l31) * 24 + fo];
      {  // Q: TRANSPOSED -> A = Wq, B = X
        short8 wh8 = *(const short8*)&Wf[l31 * 136 + wfo];
        aQ = MFMA(wh8, xh, aQ, 0, 0, 0);
      }
      {  // K: A = X, B = Wk
        short8 wh8 = *(const short8*)&Wf[(32 + l31) * 136 + wfo];
        aK = MFMA(xh, wh8, aK, 0, 0, 0);
      }
      {  // V: A = X, B = Wv
        short8 wh8 = *(const short8*)&Wf[(64 + l31) * 136 + wfo];
        aV = MFMA(xh, wh8, aV, 0, 0, 0);
      }
    }
  }

  __syncthreads();  // all X/W reads done; safe to overwrite with K/V

  // ---- Q^T acc -> phase-2 B-fragment, fully in registers ----
  const float QS = 0.17677669529663687f * 1.4426950408889634f;  // /sqrt(32)*log2e
  uint4v qA = {0, 0, 0, 0}, qB = {0, 0, 0, 0};
  const int swz = ((l31 >> 3) & 3) << 3;
  if (act) {
    unsigned g0 = cvtpk_bf16(aQ[0] * QS, aQ[1] * QS);
    unsigned g1 = cvtpk_bf16(aQ[2] * QS, aQ[3] * QS);
    unsigned g2 = cvtpk_bf16(aQ[4] * QS, aQ[5] * QS);
    unsigned g3 = cvtpk_bf16(aQ[6] * QS, aQ[7] * QS);
    unsigned g4 = cvtpk_bf16(aQ[8] * QS, aQ[9] * QS);
    unsigned g5 = cvtpk_bf16(aQ[10] * QS, aQ[11] * QS);
    unsigned g6 = cvtpk_bf16(aQ[12] * QS, aQ[13] * QS);
    unsigned g7 = cvtpk_bf16(aQ[14] * QS, aQ[15] * QS);
    swap32(g0, g2); swap32(g1, g3); swap32(g4, g6); swap32(g5, g7);
    qA[0] = g0; qA[1] = g1; qA[2] = g2; qA[3] = g3;
    qB[0] = g4; qB[1] = g5; qB[2] = g6; qB[3] = g7;

    // K -> LDS (2-bit XOR col swizzle)
#pragma unroll
    for (int r = 0; r < 16; ++r) {
      int iD = (r & 3) + ((r >> 2) << 3) + (half << 2);
      int cs = l31 ^ ((r >> 2) << 3);
      Kb[(wv * 32 + iD) * 40 + cs] = bf16u(aK[r]);
    }
    // V -> LDS transposed, stride 360, token-swizzled by (d&24)
#pragma unroll
    for (int r = 0; r < 16; r += 2) {
      int j0 = (r & 3) + ((r >> 2) << 3) + (half << 2);
      *(unsigned*)&Vt[l31 * 360 + wv * 32 + (j0 ^ swz)] =
          cvtpk_bf16(aV[r], aV[r + 1]);
    }
  }
  __syncthreads();

  // ---------------- Phase 2: attention ----------------
  if (act) {
    const float* bp = prep + ((size_t)(h * 22 + half) * NP) * 16;
    float* outw = out + (size_t)w * N * DIM + h * DH;
    attend(wv * 32, qA, qB, Kb, Vt, bp, outw, l31, half, swz);
  }
}

// ---------------------------------------------------------------------------
// Kernel 3: out-projection, in-place on d_out. O-lo dropped (R17; W2 keeps
// hi/lo). One block per window, 768 threads (12 waves), M-tile per wave.
// ---------------------------------------------------------------------------
__global__ __launch_bounds__(768, 3) void proj_kernel(
    const float* __restrict__ wout, float* __restrict__ out) {
  const int w = blockIdx.x;
  const int tid = threadIdx.x;
  const int lane = tid & 63, wv = tid >> 6, l31 = lane & 31, half = lane >> 5;
  __shared__ __align__(16) unsigned short lds[24320];     // 48640 B
  unsigned short* Oh = lds;               // [352][40]
  unsigned short* W2h = lds + 14080;      // [128][40]
  unsigned short* W2l = lds + 19200;      // [128][40]
  float* ow = out + (size_t)w * N * DIM;
  const int swz = ((l31 >> 3) & 3) << 3;
  const bool act = (wv < 11);

  f32x16 acc[4];
#pragma unroll
  for (int s = 0; s < 4; ++s)
#pragma unroll
    for (int r = 0; r < 16; ++r) acc[s][r] = 0.f;

  for (int kc = 0; kc < 4; ++kc) {
    __syncthreads();
    // O staging: 2816 quad-groups (hi only)
#pragma unroll
    for (int p = 0; p < 4; ++p) {
      int idx = tid + p * 768;
      if (idx < 2816) {
        int row = idx >> 3, g = (idx & 7) << 2;
        float4v v = {0.f, 0.f, 0.f, 0.f};
        if (row < N) v = *(const float4v*)(ow + row * DIM + kc * 32 + g);
        unsigned h0 = cvtpk_bf16(v[0], v[1]);
        unsigned h1 = cvtpk_bf16(v[2], v[3]);
        uint2v hv = {h0, h1};
        int gs = g ^ (((row >> 3) & 3) << 3);
        *(uint2v*)&Oh[row * 40 + gs] = hv;
      }
    }
    // W2 staging: 1024 quad-jobs (float4 along n, transposed scalar writes)
#pragma unroll
    for (int p = 0; p < 2; ++p) {
      int idx = tid + p * 768;
      if (idx < 1024) {
        int k = idx >> 5, n4 = (idx & 31) << 2;
        float4v v = *(const float4v*)(wout + (size_t)(kc * 32 + k) * DIM + n4);
#pragma unroll
        for (int u = 0; u < 4; ++u) {
          int n = n4 + u;
          int ks = k ^ (((n >> 3) & 3) << 3);
          unsigned short hv = bf16u(v[u]);
          W2h[n * 40 + ks] = hv;
          W2l[n * 40 + ks] =
              bf16u(v[u] - __builtin_bit_cast(float, (unsigned)hv << 16));
        }
      }
    }
    __syncthreads();
    if (act) {
#pragma unroll
      for (int kk = 0; kk < 2; ++kk) {
        int ro = (kk * 16 + half * 8) ^ swz;
        int rb = (wv * 32 + l31) * 40 + ro;
        short8 ah = *(const short8*)&Oh[rb];
#pragma unroll
        for (int s = 0; s < 4; ++s) {
          int wb = (s * 32 + l31) * 40 + ro;
          short8 bh = *(const short8*)&W2h[wb];
          short8 bl = *(const short8*)&W2l[wb];
          acc[s] = MFMA(ah, bh, acc[s], 0, 0, 0);
          acc[s] = MFMA(ah, bl, acc[s], 0, 0, 0);
        }
      }
    }
  }
  if (act) {
#pragma unroll
    for (int s = 0; s < 4; ++s) {
#pragma unroll
      for (int r = 0; r < 16; ++r) {
        int iD = (r & 3) + ((r >> 2) << 3) + (half << 2);
        int i = wv * 32 + iD;
        if (i < N) ow[(size_t)i * DIM + s * 32 + l31] = acc[s][r];
      }
    }
  }
}

// ---------------------------------------------------------------------------
extern "C" void kernel_launch(void* const* d_in, const int* in_sizes, int n_in,
                              void* d_out, int out_size, void* d_ws, size_t ws_size,
                              hipStream_t stream) {
  const float* x     = (const float*)d_in[0];
  const float* wqkv  = (const float*)d_in[1];
  const float* wout  = (const float*)d_in[2];
  const float* table = (const float*)d_in[3];
  const int*   rel   = (const int*)d_in[4];
  float* out  = (float*)d_out;
  float* prep = (float*)d_ws;  // 4*11*2*352*16*4 B = 1.98 MB

  const int B = in_sizes[0] / (N * DIM);  // 512 windows
  const int rows = HEADS * 11 * 2 * NP;   // 30976

  bias_kernel<<<(rows + 255) / 256, 256, 0, stream>>>(table, rel, prep);
  attn_kernel<<<HEADS * B, 768, 0, stream>>>(x, wqkv, prep, out);
  proj_kernel<<<B, 768, 0, stream>>>(wout, out);
}

// Round 19
// 166.569 us; speedup vs baseline: 1.2792x; 1.0425x over previous
//
#include <hip/hip_runtime.h>

#define N 343        // 7*7*7 tokens per window
#define NP 352       // padded to 11 tiles of 32
#define DIM 128
#define HEADS 4
#define DH 32

typedef float  f32x16 __attribute__((ext_vector_type(16)));
typedef float  float4v __attribute__((ext_vector_type(4)));
typedef short  short8 __attribute__((ext_vector_type(8)));
typedef unsigned uint4v __attribute__((ext_vector_type(4)));
typedef unsigned uint2v __attribute__((ext_vector_type(2)));

#define MFMA __builtin_amdgcn_mfma_f32_32x32x16_bf16

// ---- gfx950 packed bf16 convert (RNE) and cross-half swap -----------------
static __device__ __forceinline__ unsigned cvtpk_bf16(float lo, float hi) {
  unsigned r;
  asm("v_cvt_pk_bf16_f32 %0, %1, %2" : "=v"(r) : "v"(lo), "v"(hi));
  return r;
}
static __device__ __forceinline__ void swap32(unsigned &a, unsigned &b) {
  asm("v_permlane32_swap_b32 %0, %1" : "+v"(a), "+v"(b));
}
// native base-2 exponential (v_exp_f32 IS exp2 on CDNA)
static __device__ __forceinline__ float exp2v(float x) {
  float r;
  asm("v_exp_f32 %0, %1" : "=v"(r) : "v"(x));
  return r;
}
// 3-input max, single VOP3 instruction
static __device__ __forceinline__ float max3v(float a, float b, float c) {
  float r;
  asm("v_max3_f32 %0, %1, %2, %3" : "=v"(r) : "v"(a), "v"(b), "v"(c));
  return r;
}
static __device__ __forceinline__ unsigned short bf16u(float a) {
  unsigned u = __builtin_bit_cast(unsigned, a);
  unsigned r = u + 0x7fffu + ((u >> 16) & 1u);
  return (unsigned short)(r >> 16);
}

// ---------------------------------------------------------------------------
// Kernel 1: bias gather pre-permuted into the 32x32 MFMA C-fragment order.
// ---------------------------------------------------------------------------
__global__ __launch_bounds__(256) void bias_kernel(
    const float* __restrict__ table, const int* __restrict__ rel,
    float* __restrict__ prep) {
  int row = blockIdx.x * 256 + threadIdx.x;
  if (row >= HEADS * 11 * 2 * NP) return;
  int i = row % NP;
  int t = row / NP;
  int half = t & 1;
  int tj = t >> 1;
  int jt = tj % 11;
  int h = tj / 11;
  float* dst = prep + (size_t)row * 16;
#pragma unroll
  for (int r = 0; r < 16; ++r) {
    int j = jt * 32 + (r & 3) + ((r >> 2) << 3) + (half << 2);
    float v;
    if (j >= N) v = -1.44e30f;
    else if (i >= N) v = 0.f;
    else v = table[rel[i * N + j] * HEADS + h] * 1.4426950408889634f;
    dst[r] = v;
  }
}

// ---------------------------------------------------------------------------
// Phase-2 flash loop, one 32-row M-tile, Q in registers. Max-tracked online
// softmax (no-max failed twice — permanent). NEW: v_max3_f32 tree (8 ops,
// depth 3 vs 15 ops depth 4) shortens the serial MFMA->max->shfl->exp chain.
// Kb: [352][40] col-swizzled by (row&24). Vt: [32][360] token-swizzled
// (d&24). Bank conflicts NOT on the critical path (measured R11 vs R14).
// ---------------------------------------------------------------------------
static __device__ __forceinline__ void attend(
    int i0, uint4v qAu, uint4v qBu,
    const unsigned short* __restrict__ Kb, const unsigned short* __restrict__ Vt,
    const float* __restrict__ bp, float* __restrict__ outw,
    int l31, int half, int swz) {
  short8 q0 = __builtin_bit_cast(short8, qAu);
  short8 q1 = __builtin_bit_cast(short8, qBu);
  const float* bpi = bp + (size_t)(i0 + l31) * 16;

  f32x16 O;
#pragma unroll
  for (int r = 0; r < 16; ++r) O[r] = 0.f;
  float m_run = -3.0e38f, l_run = 0.f;

  f32x16 Tn = *(const f32x16*)(bpi);      // prefetch bias tile 0
  for (int jt = 0; jt < 11; ++jt) {
    f32x16 T = Tn;                        // bias IS the MFMA C-input
    if (jt < 10) Tn = *(const f32x16*)(bpi + (size_t)(jt + 1) * 11264);

    const int krow = (jt * 32 + l31) * 40;
    short8 ka0 = *(const short8*)&Kb[krow + ((half * 8) ^ swz)];
    short8 ka1 = *(const short8*)&Kb[krow + ((half * 8 + 16) ^ swz)];
    T = MFMA(ka0, q0, T, 0, 0, 0);
    T = MFMA(ka1, q1, T, 0, 0, 0);

    // row max via v_max3 tree: 5 + 2 + 1 = 8 ops, depth 3
    float g0 = max3v(T[0],  T[1],  T[2]);
    float g1 = max3v(T[3],  T[4],  T[5]);
    float g2 = max3v(T[6],  T[7],  T[8]);
    float g3 = max3v(T[9],  T[10], T[11]);
    float g4 = max3v(T[12], T[13], T[14]);
    float h0 = max3v(g0, g1, g2);
    float h1 = max3v(g3, g4, T[15]);
    float pm = fmaxf(h0, h1);
    pm = fmaxf(pm, __shfl_xor(pm, 32, 64));

    if (__any(pm > m_run + 11.5f)) {      // deferred-max rescale (rare)
      float nm = fmaxf(m_run, pm);
      float f = exp2v(m_run - nm);
      l_run *= f;
      m_run = nm;
#pragma unroll
      for (int r = 0; r < 16; ++r) {
        int iD = (r & 3) + ((r >> 2) << 3) + (half << 2);
        O[r] *= __shfl(f, iD, 64);
      }
    }

    float p[16];
#pragma unroll
    for (int r = 0; r < 16; ++r) p[r] = exp2v(T[r] - m_run);
    float s0 = (p[0] + p[1]) + (p[2] + p[3]);
    float s1 = (p[4] + p[5]) + (p[6] + p[7]);
    float s2 = (p[8] + p[9]) + (p[10] + p[11]);
    float s3 = (p[12] + p[13]) + (p[14] + p[15]);
    float ps = (s0 + s1) + (s2 + s3);
    l_run += ps + __shfl_xor(ps, 32, 64);

    unsigned k0 = cvtpk_bf16(p[0], p[1]),   k1 = cvtpk_bf16(p[2], p[3]);
    unsigned k2 = cvtpk_bf16(p[4], p[5]),   k3 = cvtpk_bf16(p[6], p[7]);
    unsigned k4 = cvtpk_bf16(p[8], p[9]),   k5 = cvtpk_bf16(p[10], p[11]);
    unsigned k6 = cvtpk_bf16(p[12], p[13]), k7 = cvtpk_bf16(p[14], p[15]);
    swap32(k0, k2); swap32(k1, k3); swap32(k4, k6); swap32(k5, k7);
    uint4v u1 = {k0, k1, k2, k3};
    uint4v u2 = {k4, k5, k6, k7};
    short8 pa1 = __builtin_bit_cast(short8, u1);
    short8 pa2 = __builtin_bit_cast(short8, u2);

    const int vrow = l31 * 360 + jt * 32;
    short8 vb1 = *(const short8*)&Vt[vrow + ((half * 8) ^ swz)];
    short8 vb2 = *(const short8*)&Vt[vrow + ((half * 8 + 16) ^ swz)];
    O = MFMA(pa1, vb1, O, 0, 0, 0);
    O = MFMA(pa2, vb2, O, 0, 0, 0);
  }

  float inv = 1.0f / l_run;
#pragma unroll
  for (int r = 0; r < 16; ++r) {
    int iD = (r & 3) + ((r >> 2) << 3) + (half << 2);
    float invr = __shfl(inv, iD, 64);
    int i = i0 + iD;
    if (i < N) outw[(size_t)i * DIM + l31] = O[r] * invr;
  }
}

// ---------------------------------------------------------------------------
// Kernel 2: fused QKV projection + attention. One block per (window, head),
// 768 threads = 12 waves, one M-tile per wave (wave 11 = staging helper).
// W (head slice, 24KB bf16) staged ONCE into resident LDS Wf[96][136]
// (68 dw == 4 mod 32 -> conflict-free, no swizzle); X double-buffered ->
// one barrier per kc; T14 load-issue placement.
// ---------------------------------------------------------------------------
__global__ __launch_bounds__(768, 3) void attn_kernel(
    const float* __restrict__ x, const float* __restrict__ wqkv,
    const float* __restrict__ prep, float* __restrict__ out) {
  const int b = blockIdx.x;
  const int sw = (b & 7) * ((int)gridDim.x >> 3) + (b >> 3);  // XCD swizzle
  const int h = sw & 3;
  const int w = sw >> 2;
  const int tid = threadIdx.x;
  const int lane = tid & 63;
  const int wv = tid >> 6;        // 0..11
  const int l31 = lane & 31;
  const int half = lane >> 5;

  __shared__ __align__(16) unsigned short lds[29952];   // 59904 B
  unsigned short* Xb0 = lds;            // [352][24]  (phase 1, buf 0)
  unsigned short* Xb1 = lds + 8448;     // [352][24]  (phase 1, buf 1)
  unsigned short* Wf  = lds + 16896;    // [96][136]  (phase 1, resident W)
  unsigned short* Kb = lds;             // [352][40]  (phase 2, aliased)
  unsigned short* Vt = lds + 14080;     // [32][360]

  const float* xw = x + (size_t)w * (N * DIM);
  const int xsw = ((l31 >> 3) & 1) << 3;   // 1-bit swizzle for X frag reads
  const bool act = (wv < 11);

  // ---- staging geometry (fixed per thread) ----
  const int xrow0 = tid >> 2,  xg0 = (tid & 3) << 2;           // job 0 (all)
  const int idx1  = tid + 768;
  const int xrow1 = idx1 >> 2, xg1 = (idx1 & 3) << 2;          // job 1
  const bool hasx1 = (idx1 < 1408);
  const int xgs0 = xg0 ^ (((xrow0 >> 3) & 1) << 3);
  const int xgs1 = xg1 ^ (((xrow1 >> 3) & 1) << 3);

  float4v xr0v = {0.f, 0.f, 0.f, 0.f}, xr1v = {0.f, 0.f, 0.f, 0.f};

#define LOAD_STAGE(kc_)                                                     \
  {                                                                         \
    xr0v = *(const float4v*)(xw + xrow0 * DIM + (kc_) * 16 + xg0);          \
    xr1v[0] = 0.f; xr1v[1] = 0.f; xr1v[2] = 0.f; xr1v[3] = 0.f;             \
    if (hasx1 && xrow1 < N)                                                 \
      xr1v = *(const float4v*)(xw + xrow1 * DIM + (kc_) * 16 + xg1);        \
  }

#define WRITE_STAGE(XB_)                                                    \
  {                                                                         \
    unsigned h0_, h1_;                                                      \
    h0_ = cvtpk_bf16(xr0v[0], xr0v[1]);                                     \
    h1_ = cvtpk_bf16(xr0v[2], xr0v[3]);                                     \
    uint2v hv_ = {h0_, h1_};                                                \
    *(uint2v*)&(XB_)[xrow0 * 24 + xgs0] = hv_;                              \
    if (hasx1) {                                                            \
      h0_ = cvtpk_bf16(xr1v[0], xr1v[1]);                                   \
      h1_ = cvtpk_bf16(xr1v[2], xr1v[3]);                                   \
      uint2v hv2_ = {h0_, h1_};                                             \
      *(uint2v*)&(XB_)[xrow1 * 24 + xgs1] = hv2_;                           \
    }                                                                       \
  }

  f32x16 aQ, aK, aV;
#pragma unroll
  for (int r = 0; r < 16; ++r) { aQ[r] = 0.f; aK[r] = 0.f; aV[r] = 0.f; }

  // ---------------- Phase 1 prologue: X chunk 0 + resident W ----------------
  LOAD_STAGE(0);
  // one-time W stage: 3072 jobs (c 0..95, k-groups of 4)
#pragma unroll
  for (int p = 0; p < 4; ++p) {
    int idx = tid + p * 768;
    int c = idx % 96, kg = (idx / 96) << 2;
    int col = ((c >> 5) << 7) + h * DH + (c & 31);
    const float* wp = wqkv + (size_t)kg * 384 + col;
#pragma unroll
    for (int u = 0; u < 4; ++u)
      Wf[c * 136 + kg + u] = bf16u(wp[(size_t)u * 384]);
  }

  // ---------------- Phase 1 main: one barrier per kc ----------------
  for (int kc = 0; kc < 8; ++kc) {
    unsigned short* cur = (kc & 1) ? Xb1 : Xb0;
    WRITE_STAGE(cur);                 // regs from LOAD of last iter
    if (kc < 7) LOAD_STAGE(kc + 1);   // issue next chunk's loads NOW
    __syncthreads();                  // cur visible; (kc-2) reads retired

    if (act) {
      const int fo = (half * 8) ^ xsw;
      const int wfo = kc * 16 + half * 8;
      short8 xh = *(const short8*)&cur[(wv * 32 + l31) * 24 + fo];
      {  // Q: TRANSPOSED -> A = Wq, B = X
        short8 wh8 = *(const short8*)&Wf[l31 * 136 + wfo];
        aQ = MFMA(wh8, xh, aQ, 0, 0, 0);
      }
      {  // K: A = X, B = Wk
        short8 wh8 = *(const short8*)&Wf[(32 + l31) * 136 + wfo];
        aK = MFMA(xh, wh8, aK, 0, 0, 0);
      }
      {  // V: A = X, B = Wv
        short8 wh8 = *(const short8*)&Wf[(64 + l31) * 136 + wfo];
        aV = MFMA(xh, wh8, aV, 0, 0, 0);
      }
    }
  }

  __syncthreads();  // all X/W reads done; safe to overwrite with K/V

  // ---- Q^T acc -> phase-2 B-fragment, fully in registers ----
  const float QS = 0.17677669529663687f * 1.4426950408889634f;  // /sqrt(32)*log2e
  uint4v qA = {0, 0, 0, 0}, qB = {0, 0, 0, 0};
  const int swz = ((l31 >> 3) & 3) << 3;
  if (act) {
    unsigned g0 = cvtpk_bf16(aQ[0] * QS, aQ[1] * QS);
    unsigned g1 = cvtpk_bf16(aQ[2] * QS, aQ[3] * QS);
    unsigned g2 = cvtpk_bf16(aQ[4] * QS, aQ[5] * QS);
    unsigned g3 = cvtpk_bf16(aQ[6] * QS, aQ[7] * QS);
    unsigned g4 = cvtpk_bf16(aQ[8] * QS, aQ[9] * QS);
    unsigned g5 = cvtpk_bf16(aQ[10] * QS, aQ[11] * QS);
    unsigned g6 = cvtpk_bf16(aQ[12] * QS, aQ[13] * QS);
    unsigned g7 = cvtpk_bf16(aQ[14] * QS, aQ[15] * QS);
    swap32(g0, g2); swap32(g1, g3); swap32(g4, g6); swap32(g5, g7);
    qA[0] = g0; qA[1] = g1; qA[2] = g2; qA[3] = g3;
    qB[0] = g4; qB[1] = g5; qB[2] = g6; qB[3] = g7;

    // K -> LDS (2-bit XOR col swizzle)
#pragma unroll
    for (int r = 0; r < 16; ++r) {
      int iD = (r & 3) + ((r >> 2) << 3) + (half << 2);
      int cs = l31 ^ ((r >> 2) << 3);
      Kb[(wv * 32 + iD) * 40 + cs] = bf16u(aK[r]);
    }
    // V -> LDS transposed, stride 360, token-swizzled by (d&24)
#pragma unroll
    for (int r = 0; r < 16; r += 2) {
      int j0 = (r & 3) + ((r >> 2) << 3) + (half << 2);
      *(unsigned*)&Vt[l31 * 360 + wv * 32 + (j0 ^ swz)] =
          cvtpk_bf16(aV[r], aV[r + 1]);
    }
  }
  __syncthreads();

  // ---------------- Phase 2: attention ----------------
  if (act) {
    const float* bp = prep + ((size_t)(h * 22 + half) * NP) * 16;
    float* outw = out + (size_t)w * N * DIM + h * DH;
    attend(wv * 32, qA, qB, Kb, Vt, bp, outw, l31, half, swz);
  }
}

// ---------------------------------------------------------------------------
// Kernel 3: out-projection, in-place on d_out. NEW: W2-lo also dropped ->
// pure bf16 GEMM (1 MFMA per (kk,s)), W2 staging halved. Error budget:
// bf16-W2 rounding adds ~3-4e-3 through the 128-dot; combined ~0.013-0.015
// vs 0.0242 threshold. One block per window, 768 threads, M-tile per wave.
// ---------------------------------------------------------------------------
__global__ __launch_bounds__(768, 3) void proj_kernel(
    const float* __restrict__ wout, float* __restrict__ out) {
  const int w = blockIdx.x;
  const int tid = threadIdx.x;
  const int lane = tid & 63, wv = tid >> 6, l31 = lane & 31, half = lane >> 5;
  __shared__ __align__(16) unsigned short lds[19200];     // 38400 B
  unsigned short* Oh = lds;               // [352][40]
  unsigned short* W2h = lds + 14080;      // [128][40]
  float* ow = out + (size_t)w * N * DIM;
  const int swz = ((l31 >> 3) & 3) << 3;
  const bool act = (wv < 11);

  f32x16 acc[4];
#pragma unroll
  for (int s = 0; s < 4; ++s)
#pragma unroll
    for (int r = 0; r < 16; ++r) acc[s][r] = 0.f;

  for (int kc = 0; kc < 4; ++kc) {
    __syncthreads();
    // O staging: 2816 quad-groups (hi only)
#pragma unroll
    for (int p = 0; p < 4; ++p) {
      int idx = tid + p * 768;
      if (idx < 2816) {
        int row = idx >> 3, g = (idx & 7) << 2;
        float4v v = {0.f, 0.f, 0.f, 0.f};
        if (row < N) v = *(const float4v*)(ow + row * DIM + kc * 32 + g);
        unsigned h0 = cvtpk_bf16(v[0], v[1]);
        unsigned h1 = cvtpk_bf16(v[2], v[3]);
        uint2v hv = {h0, h1};
        int gs = g ^ (((row >> 3) & 3) << 3);
        *(uint2v*)&Oh[row * 40 + gs] = hv;
      }
    }
    // W2 staging: 1024 quad-jobs (hi only)
#pragma unroll
    for (int p = 0; p < 2; ++p) {
      int idx = tid + p * 768;
      if (idx < 1024) {
        int k = idx >> 5, n4 = (idx & 31) << 2;
        float4v v = *(const float4v*)(wout + (size_t)(kc * 32 + k) * DIM + n4);
#pragma unroll
        for (int u = 0; u < 4; ++u) {
          int n = n4 + u;
          int ks = k ^ (((n >> 3) & 3) << 3);
          W2h[n * 40 + ks] = bf16u(v[u]);
        }
      }
    }
    __syncthreads();
    if (act) {
#pragma unroll
      for (int kk = 0; kk < 2; ++kk) {
        int ro = (kk * 16 + half * 8) ^ swz;
        int rb = (wv * 32 + l31) * 40 + ro;
        short8 ah = *(const short8*)&Oh[rb];
#pragma unroll
        for (int s = 0; s < 4; ++s) {
          short8 bh = *(const short8*)&W2h[(s * 32 + l31) * 40 + ro];
          acc[s] = MFMA(ah, bh, acc[s], 0, 0, 0);
        }
      }
    }
  }
  if (act) {
#pragma unroll
    for (int s = 0; s < 4; ++s) {
#pragma unroll
      for (int r = 0; r < 16; ++r) {
        int iD = (r & 3) + ((r >> 2) << 3) + (half << 2);
        int i = wv * 32 + iD;
        if (i < N) ow[(size_t)i * DIM + s * 32 + l31] = acc[s][r];
      }
    }
  }
}

// ---------------------------------------------------------------------------
extern "C" void kernel_launch(void* const* d_in, const int* in_sizes, int n_in,
                              void* d_out, int out_size, void* d_ws, size_t ws_size,
                              hipStream_t stream) {
  const float* x     = (const float*)d_in[0];
  const float* wqkv  = (const float*)d_in[1];
  const float* wout  = (const float*)d_in[2];
  const float* table = (const float*)d_in[3];
  const int*   rel   = (const int*)d_in[4];
  float* out  = (float*)d_out;
  float* prep = (float*)d_ws;  // 4*11*2*352*16*4 B = 1.98 MB

  const int B = in_sizes[0] / (N * DIM);  // 512 windows
  const int rows = HEADS * 11 * 2 * NP;   // 30976

  bias_kernel<<<(rows + 255) / 256, 256, 0, stream>>>(table, rel, prep);
  attn_kernel<<<HEADS * B, 768, 0, stream>>>(x, wqkv, prep, out);
  proj_kernel<<<B, 768, 0, stream>>>(wout, out);
}